// Round 9
// baseline (427.673 us; speedup 1.0000x reference)
//
#include <hip/hip_runtime.h>
#include <math.h>

#define TPB 256
#define NEG_SLOPE 0.2f
#define COS_EPS 1e-8f
#define NH 6
#define GSTRIDE 68   // LDS row stride (floats) for GEMM tiles
#define DCACHE 12    // neighbor rows cached in registers per node
#define SALS 8       // sal row stride (floats), 32B-aligned

// ---------- helpers ----------
__device__ inline float wave_sum64(float v) {
  #pragma unroll
  for (int off = 32; off > 0; off >>= 1) v += __shfl_down(v, off);
  return __shfl(v, 0);
}
__device__ inline float wave_max64(float v) {
  #pragma unroll
  for (int off = 32; off > 0; off >>= 1) v = fmaxf(v, __shfl_down(v, off));
  return __shfl(v, 0);
}
__device__ inline unsigned short f2bf(float f) {
  unsigned u = __float_as_uint(f);
  unsigned r = (u + 0x7fffu + ((u >> 16) & 1u)) >> 16;   // RNE
  return (unsigned short)r;
}
__device__ inline float bf2f(unsigned short b) {
  return __uint_as_float(((unsigned)b) << 16);
}
__device__ inline unsigned packbf(float lo, float hi) {
  return (unsigned)f2bf(lo) | ((unsigned)f2bf(hi) << 16);
}
__device__ inline float bflo(unsigned u) { return __uint_as_float(u << 16); }
__device__ inline float bfhi(unsigned u) { return __uint_as_float(u & 0xffff0000u); }

#define GS_LOOP(i, total) \
  for (long i = (long)blockIdx.x * blockDim.x + threadIdx.x; i < (total); \
       i += (long)gridDim.x * blockDim.x)

// ---------- CSR build ----------
__global__ void k_cnt(const int* __restrict__ dst, const int* __restrict__ sdst,
                      int* __restrict__ gcnt, int* __restrict__ scnt,
                      long en, long sen) {
  long mx = ((en > sen ? en : sen) + 1) >> 1;
  GS_LOOP(e2, mx) {
    long e = 2 * e2;
    if (e + 1 < en) {
      int2 v = *(const int2*)&dst[e];
      atomicAdd(&gcnt[v.x], 1); atomicAdd(&gcnt[v.y], 1);
    } else if (e < en) atomicAdd(&gcnt[dst[e]], 1);
    if (e + 1 < sen) {
      int2 v = *(const int2*)&sdst[e];
      atomicAdd(&scnt[v.x], 1); atomicAdd(&scnt[v.y], 1);
    } else if (e < sen) atomicAdd(&scnt[sdst[e]], 1);
  }
}

// phase A: per-tile sums (2048 elems/block) + dinv (g-array blocks only)
__global__ __launch_bounds__(1024)
void k_scanA(const int* __restrict__ gcnt, const int* __restrict__ scnt,
             int* __restrict__ bsum, float* __restrict__ dinv, int n, int nb) {
  const int b = blockIdx.x;
  const bool isS = b >= nb;
  const int tb = isS ? b - nb : b;
  const int* cnt = isS ? scnt : gcnt;
  const int t = threadIdx.x;
  const int i0 = tb * 2048 + 2 * t;
  int v0 = (i0 < n) ? cnt[i0] : 0;
  int v1 = (i0 + 1 < n) ? cnt[i0 + 1] : 0;
  if (!isS) {
    if (i0 < n)     dinv[i0]     = rsqrtf((float)v0 + 1.0f);
    if (i0 + 1 < n) dinv[i0 + 1] = rsqrtf((float)v1 + 1.0f);
  }
  __shared__ int red[16];
  int x = v0 + v1;
  #pragma unroll
  for (int o = 32; o > 0; o >>= 1) x += __shfl_down(x, o);
  const int lane = t & 63, wv = t >> 6;
  if (lane == 0) red[wv] = x;
  __syncthreads();
  if (t < 64) {
    int w = (t < 16) ? red[t] : 0;
    #pragma unroll
    for (int o = 32; o > 0; o >>= 1) w += __shfl_down(w, o);
    if (t == 0) bsum[b] = w;
  }
}

// phase B: exclusive-scan the two halves of bsum (nb each)
__global__ void k_scanB(int* __restrict__ bsum, int nb) {
  const int lane = threadIdx.x;   // 64 threads
  if (nb <= 32) {
    int half = lane >> 5, idx = lane & 31;
    int base = half * nb;
    int v = (idx < nb) ? bsum[base + idx] : 0;
    int orig = v;
    #pragma unroll
    for (int d2 = 1; d2 < 32; d2 <<= 1) {
      int y = __shfl_up(v, d2, 32);
      if (idx >= d2) v += y;
    }
    if (idx < nb) bsum[base + idx] = v - orig;
  } else if (lane == 0) {
    int run = 0;
    for (int i = 0; i < nb; ++i) { int v = bsum[i]; bsum[i] = run; run += v; }
    run = 0;
    for (int i = 0; i < nb; ++i) { int v = bsum[nb + i]; bsum[nb + i] = run; run += v; }
  }
}

// phase C: per-tile scan + writeback of off/cur
__global__ __launch_bounds__(1024)
void k_scanC(const int* __restrict__ gcnt, int* __restrict__ goff, int* __restrict__ gcur,
             const int* __restrict__ scnt, int* __restrict__ soff, int* __restrict__ scur,
             const int* __restrict__ bsum, int n, int nb) {
  const int b = blockIdx.x;
  const bool isS = b >= nb;
  const int tb = isS ? b - nb : b;
  const int* cnt = isS ? scnt : gcnt;
  int* off = isS ? soff : goff;
  int* cur = isS ? scur : gcur;
  const int t = threadIdx.x;
  const int i0 = tb * 2048 + 2 * t;
  int v0 = (i0 < n) ? cnt[i0] : 0;
  int v1 = (i0 + 1 < n) ? cnt[i0 + 1] : 0;
  int s2 = v0 + v1;
  const int lane = t & 63, wv = t >> 6;
  int x = s2;
  #pragma unroll
  for (int d2 = 1; d2 < 64; d2 <<= 1) {
    int y = __shfl_up(x, d2);
    if (lane >= d2) x += y;
  }
  __shared__ int wsum[16];
  if (lane == 63) wsum[wv] = x;
  __syncthreads();
  if (t < 64) {
    int w = (t < 16) ? wsum[t] : 0;
    #pragma unroll
    for (int d2 = 1; d2 < 16; d2 <<= 1) {
      int y = __shfl_up(w, d2);
      if ((int)t >= d2) w += y;
    }
    if (t < 16) wsum[t] = w;
  }
  __syncthreads();
  int ex = x - s2 + (wv ? wsum[wv - 1] : 0) + bsum[b];
  if (i0 < n)     { cur[i0] = ex;          off[i0 + 1] = ex + v0; }
  if (i0 + 1 < n) { cur[i0 + 1] = ex + v0; off[i0 + 2] = ex + v0 + v1; }
  if (i0 == 0) off[0] = 0;
}

__global__ void k_scatter(const int* __restrict__ src, const int* __restrict__ dst,
                          const int* __restrict__ ssrc, const int* __restrict__ sdst,
                          int* __restrict__ gcur, int* __restrict__ gcsr,
                          int* __restrict__ scur, int* __restrict__ scsr,
                          long en, long sen) {
  long mx = ((en > sen ? en : sen) + 1) >> 1;
  GS_LOOP(e2, mx) {
    long e = 2 * e2;
    if (e + 1 < en) {
      int2 s = *(const int2*)&src[e];
      int2 d = *(const int2*)&dst[e];
      int p0 = atomicAdd(&gcur[d.x], 1); gcsr[p0] = s.x;
      int p1 = atomicAdd(&gcur[d.y], 1); gcsr[p1] = s.y;
    } else if (e < en) {
      int p = atomicAdd(&gcur[dst[e]], 1); gcsr[p] = src[e];
    }
    if (e + 1 < sen) {
      int2 s = *(const int2*)&ssrc[e];
      int2 d = *(const int2*)&sdst[e];
      int p0 = atomicAdd(&scur[d.x], 1); scsr[p0] = s.x;
      int p1 = atomicAdd(&scur[d.y], 1); scsr[p1] = s.y;
    } else if (e < sen) {
      int p = atomicAdd(&scur[sdst[e]], 1); scsr[p] = ssrc[e];
    }
  }
}

// ---------- x prescale: xb[i*32+p] = bf16pair(x[i][2p]*dinv[i], x[i][2p+1]*dinv[i])
__global__ void k_xprep(const float* __restrict__ x, const float* __restrict__ dinv,
                        unsigned* __restrict__ xb, long n) {
  GS_LOOP(idx, n * 32) {
    long i = idx >> 5; int p = (int)(idx & 31);
    float di = dinv[i];
    float2 xv = *(const float2*)&x[i * 64 + 2 * p];
    xb[idx] = packbf(xv.x * di, xv.y * di);
  }
}

// ---------- GCN aggregate on prescaled bf16 x (wave per node, paired lanes) ----
// xagg[d] = dinv[d] * sum_{s in gcsr[d]} (x[s]*dinv[s])  +  x[d]*dinv[d]^2
__global__ __launch_bounds__(256)
void k_gcn2(const int* __restrict__ goff, const int* __restrict__ gcsr,
            const unsigned* __restrict__ xb, const float* __restrict__ x,
            const float* __restrict__ dinv, float* __restrict__ xagg, int n) {
  const int lane = threadIdx.x & 63;
  const int p = lane & 31;       // channel pair
  const int hf = lane >> 5;      // which of the 2 concurrent edges
  const int d = blockIdx.x * 4 + (threadIdx.x >> 6);
  if (d >= n) return;
  const int o0 = goff[d], o1 = goff[d + 1];
  float ax = 0.f, ay = 0.f;
  for (int j = o0; j < o1; j += 2) {
    int jj = j + hf;
    if (jj < o1) {
      long s = gcsr[jj];
      unsigned u = xb[s * 32 + p];
      ax += bflo(u); ay += bfhi(u);
    }
  }
  ax += __shfl_xor(ax, 32);
  ay += __shfl_xor(ay, 32);
  if (hf == 0) {
    float di = dinv[d];
    float2 xd = *(const float2*)&x[(long)d * 64 + 2 * p];
    float2 r;
    r.x = di * ax + xd.x * di * di;
    r.y = di * ay + xd.y * di * di;
    *(float2*)&xagg[(long)d * 64 + 2 * p] = r;
  }
}

// ---------- GEMM: A[n][64] @ W[64][Mtot], 64x64 tile, 4x4 reg tile ----------
// MODE 0: fp32 out32 (+ optional bias).
// MODE 2: normalized bf16 rows (out16[r*64+c]) + bsc[r] = A_row·W2 + b2.
template <int MODE>
__global__ __launch_bounds__(256)
void k_gemm64v3(const float* __restrict__ A, const float* __restrict__ W,
                float* __restrict__ out32, unsigned short* __restrict__ out16,
                const float* __restrict__ bias,
                const float* __restrict__ W2, const float* __restrict__ b2,
                float* __restrict__ bsc, int n, int Mtot) {
  __shared__ float At[64 * GSTRIDE];
  __shared__ float Wl[64 * GSTRIDE];
  const int t  = threadIdx.x;
  const int tx = t & 15;
  const int ty = t >> 4;
  const int col0 = blockIdx.y * 64;
  const long row0 = (long)blockIdx.x * 64;

  #pragma unroll
  for (int i = 0; i < 4; ++i) {
    int k = ty + 16 * i;
    float4 wv = *(const float4*)&W[(long)k * Mtot + col0 + 4 * tx];
    *(float4*)&Wl[k * GSTRIDE + 4 * tx] = wv;
  }
  #pragma unroll
  for (int i = 0; i < 4; ++i) {
    int r = ty + 16 * i;
    long gr = row0 + r; if (gr >= n) gr = n - 1;
    float4 av = *(const float4*)&A[gr * 64 + 4 * tx];
    At[(4 * tx + 0) * GSTRIDE + r] = av.x;
    At[(4 * tx + 1) * GSTRIDE + r] = av.y;
    At[(4 * tx + 2) * GSTRIDE + r] = av.z;
    At[(4 * tx + 3) * GSTRIDE + r] = av.w;
  }
  __syncthreads();

  const int c0 = 4 * tx;
  const int r0 = 4 * ty;
  float acc[4][4] = {};
  #pragma unroll
  for (int k = 0; k < 64; ++k) {
    float4 av = *(const float4*)&At[k * GSTRIDE + r0];
    float4 wv = *(const float4*)&Wl[k * GSTRIDE + c0];
    acc[0][0] = fmaf(av.x, wv.x, acc[0][0]); acc[0][1] = fmaf(av.x, wv.y, acc[0][1]);
    acc[0][2] = fmaf(av.x, wv.z, acc[0][2]); acc[0][3] = fmaf(av.x, wv.w, acc[0][3]);
    acc[1][0] = fmaf(av.y, wv.x, acc[1][0]); acc[1][1] = fmaf(av.y, wv.y, acc[1][1]);
    acc[1][2] = fmaf(av.y, wv.z, acc[1][2]); acc[1][3] = fmaf(av.y, wv.w, acc[1][3]);
    acc[2][0] = fmaf(av.z, wv.x, acc[2][0]); acc[2][1] = fmaf(av.z, wv.y, acc[2][1]);
    acc[2][2] = fmaf(av.z, wv.z, acc[2][2]); acc[2][3] = fmaf(av.z, wv.w, acc[2][3]);
    acc[3][0] = fmaf(av.w, wv.x, acc[3][0]); acc[3][1] = fmaf(av.w, wv.y, acc[3][1]);
    acc[3][2] = fmaf(av.w, wv.z, acc[3][2]); acc[3][3] = fmaf(av.w, wv.w, acc[3][3]);
  }

  if constexpr (MODE == 0) {
    float4 bv = make_float4(0.f, 0.f, 0.f, 0.f);
    if (bias) bv = *(const float4*)&bias[col0 + c0];
    #pragma unroll
    for (int i = 0; i < 4; ++i) {
      long gr = row0 + r0 + i;
      if (gr < n)
        *(float4*)&out32[gr * Mtot + col0 + c0] =
          make_float4(acc[i][0] + bv.x, acc[i][1] + bv.y,
                      acc[i][2] + bv.z, acc[i][3] + bv.w);
    }
  }
  if constexpr (MODE == 2) {
    float p[4], q[4];
    #pragma unroll
    for (int i = 0; i < 4; ++i) {
      q[i] = acc[i][0]*acc[i][0] + acc[i][1]*acc[i][1] +
             acc[i][2]*acc[i][2] + acc[i][3]*acc[i][3];
      p[i] = At[(c0+0) * GSTRIDE + r0 + i] * W2[c0+0] +
             At[(c0+1) * GSTRIDE + r0 + i] * W2[c0+1] +
             At[(c0+2) * GSTRIDE + r0 + i] * W2[c0+2] +
             At[(c0+3) * GSTRIDE + r0 + i] * W2[c0+3];
    }
    #pragma unroll
    for (int m = 1; m < 16; m <<= 1) {
      #pragma unroll
      for (int i = 0; i < 4; ++i) { p[i] += __shfl_xor(p[i], m); q[i] += __shfl_xor(q[i], m); }
    }
    float bb = b2[0];
    #pragma unroll
    for (int i = 0; i < 4; ++i) {
      long gr = row0 + r0 + i;
      if (gr < n) {
        float rn = 1.0f / fmaxf(sqrtf(q[i]), COS_EPS);
        ushort4 v;
        v.x = f2bf(acc[i][0] * rn); v.y = f2bf(acc[i][1] * rn);
        v.z = f2bf(acc[i][2] * rn); v.w = f2bf(acc[i][3] * rn);
        *(ushort4*)&out16[gr * 64 + c0] = v;
        if (tx == 0) bsc[gr] = p[i] + bb;
      }
    }
  }
}

// ---------- h2 GEMM: all 384 cols (6 heads) per block, packed channel-major out.
__global__ __launch_bounds__(256)
void k_gemm_h2(const float* __restrict__ A, const float* __restrict__ W,
               unsigned* __restrict__ h2p, const float* __restrict__ att,
               float* __restrict__ sal, int n) {
  __shared__ float At[64 * GSTRIDE];
  __shared__ float Wl[64 * GSTRIDE];
  const int t  = threadIdx.x;
  const int tx = t & 15;
  const int ty = t >> 4;
  const long row0 = (long)blockIdx.x * 64;
  const int c0 = 4 * tx;
  const int r0 = 4 * ty;

  #pragma unroll
  for (int i = 0; i < 4; ++i) {
    int r = ty + 16 * i;
    long gr = row0 + r; if (gr >= n) gr = n - 1;
    float4 av = *(const float4*)&A[gr * 64 + 4 * tx];
    At[(4 * tx + 0) * GSTRIDE + r] = av.x;
    At[(4 * tx + 1) * GSTRIDE + r] = av.y;
    At[(4 * tx + 2) * GSTRIDE + r] = av.z;
    At[(4 * tx + 3) * GSTRIDE + r] = av.w;
  }
  float4 wr[4];
  #pragma unroll
  for (int i = 0; i < 4; ++i)
    wr[i] = *(const float4*)&W[(long)(ty + 16 * i) * 384 + 4 * tx];

  float4 acc[6][4];
  #pragma unroll
  for (int h = 0; h < 6; ++h)
    #pragma unroll
    for (int i = 0; i < 4; ++i) acc[h][i] = make_float4(0.f, 0.f, 0.f, 0.f);

  #pragma unroll
  for (int head = 0; head < 6; ++head) {
    #pragma unroll
    for (int i = 0; i < 4; ++i)
      *(float4*)&Wl[(ty + 16 * i) * GSTRIDE + 4 * tx] = wr[i];
    __syncthreads();
    if (head < 5) {
      #pragma unroll
      for (int i = 0; i < 4; ++i)
        wr[i] = *(const float4*)&W[(long)(ty + 16 * i) * 384 + (head + 1) * 64 + 4 * tx];
    }
    #pragma unroll 16
    for (int k = 0; k < 64; ++k) {
      float4 av = *(const float4*)&At[k * GSTRIDE + r0];
      float4 wv = *(const float4*)&Wl[k * GSTRIDE + c0];
      acc[head][0].x = fmaf(av.x, wv.x, acc[head][0].x);
      acc[head][0].y = fmaf(av.x, wv.y, acc[head][0].y);
      acc[head][0].z = fmaf(av.x, wv.z, acc[head][0].z);
      acc[head][0].w = fmaf(av.x, wv.w, acc[head][0].w);
      acc[head][1].x = fmaf(av.y, wv.x, acc[head][1].x);
      acc[head][1].y = fmaf(av.y, wv.y, acc[head][1].y);
      acc[head][1].z = fmaf(av.y, wv.z, acc[head][1].z);
      acc[head][1].w = fmaf(av.y, wv.w, acc[head][1].w);
      acc[head][2].x = fmaf(av.z, wv.x, acc[head][2].x);
      acc[head][2].y = fmaf(av.z, wv.y, acc[head][2].y);
      acc[head][2].z = fmaf(av.z, wv.z, acc[head][2].z);
      acc[head][2].w = fmaf(av.z, wv.w, acc[head][2].w);
      acc[head][3].x = fmaf(av.w, wv.x, acc[head][3].x);
      acc[head][3].y = fmaf(av.w, wv.y, acc[head][3].y);
      acc[head][3].z = fmaf(av.w, wv.z, acc[head][3].z);
      acc[head][3].w = fmaf(av.w, wv.w, acc[head][3].w);
    }
    __syncthreads();
  }

  #pragma unroll
  for (int i = 0; i < 4; ++i) {
    long gr = row0 + r0 + i;
    if (gr < n) {
      uint4 u0, u1, u2;
      u0.x = packbf(acc[0][i].x, acc[1][i].x);
      u0.y = packbf(acc[2][i].x, acc[3][i].x);
      u0.z = packbf(acc[4][i].x, acc[5][i].x);
      u0.w = packbf(acc[0][i].y, acc[1][i].y);
      u1.x = packbf(acc[2][i].y, acc[3][i].y);
      u1.y = packbf(acc[4][i].y, acc[5][i].y);
      u1.z = packbf(acc[0][i].z, acc[1][i].z);
      u1.w = packbf(acc[2][i].z, acc[3][i].z);
      u2.x = packbf(acc[4][i].z, acc[5][i].z);
      u2.y = packbf(acc[0][i].w, acc[1][i].w);
      u2.z = packbf(acc[2][i].w, acc[3][i].w);
      u2.w = packbf(acc[4][i].w, acc[5][i].w);
      unsigned* dstp = &h2p[gr * 192 + c0 * 3];
      *(uint4*)(dstp + 0) = u0;
      *(uint4*)(dstp + 4) = u1;
      *(uint4*)(dstp + 8) = u2;
    }
  }
  #pragma unroll
  for (int head = 0; head < 6; ++head) {
    float a0 = att[head * 128 + c0 + 0], a1 = att[head * 128 + c0 + 1];
    float a2 = att[head * 128 + c0 + 2], a3 = att[head * 128 + c0 + 3];
    float p[4];
    #pragma unroll
    for (int i = 0; i < 4; ++i)
      p[i] = acc[head][i].x * a0 + acc[head][i].y * a1 +
             acc[head][i].z * a2 + acc[head][i].w * a3;
    #pragma unroll
    for (int m = 1; m < 16; m <<= 1) {
      #pragma unroll
      for (int i = 0; i < 4; ++i) p[i] += __shfl_xor(p[i], m);
    }
    if (tx == 0) {
      #pragma unroll
      for (int i = 0; i < 4; ++i) {
        long gr = row0 + r0 + i;
        if (gr < n) sal[gr * SALS + head] = p[i];
      }
    }
  }
}

// ---------- fused attention mega-kernel (wave per node) ----------
__global__ __launch_bounds__(256)
void k_mega(const int* __restrict__ soff, const int* __restrict__ scsr,
            const unsigned* __restrict__ h2p, const float* __restrict__ sal,
            const float* __restrict__ att, float* __restrict__ xm, int n) {
  const int lane = threadIdx.x & 63;
  const int d = blockIdx.x * 4 + (threadIdx.x >> 6);
  if (d >= n) return;
  const int o0 = soff[d], o1 = soff[d + 1];
  const int deg = o1 - o0;

  unsigned ck0[DCACHE], ck1[DCACHE], ck2[DCACHE];
  float hm[NH];
  #pragma unroll
  for (int h = 0; h < NH; ++h) hm[h] = -INFINITY;
  #pragma unroll
  for (int idx = 0; idx < DCACHE; ++idx) {
    unsigned u0 = 0, u1 = 0, u2 = 0;
    if (idx < deg) {
      long s = scsr[o0 + idx];
      const unsigned* rp = &h2p[s * 192 + lane * 3];
      u0 = rp[0]; u1 = rp[1]; u2 = rp[2];
      hm[0] = fmaxf(hm[0], bflo(u0)); hm[1] = fmaxf(hm[1], bfhi(u0));
      hm[2] = fmaxf(hm[2], bflo(u1)); hm[3] = fmaxf(hm[3], bfhi(u1));
      hm[4] = fmaxf(hm[4], bflo(u2)); hm[5] = fmaxf(hm[5], bfhi(u2));
    }
    ck0[idx] = u0; ck1[idx] = u1; ck2[idx] = u2;
  }
  for (int j = o0 + DCACHE; j < o1; ++j) {
    long s = scsr[j];
    const unsigned* rp = &h2p[s * 192 + lane * 3];
    unsigned u0 = rp[0], u1 = rp[1], u2 = rp[2];
    hm[0] = fmaxf(hm[0], bflo(u0)); hm[1] = fmaxf(hm[1], bfhi(u0));
    hm[2] = fmaxf(hm[2], bflo(u1)); hm[3] = fmaxf(hm[3], bfhi(u1));
    hm[4] = fmaxf(hm[4], bflo(u2)); hm[5] = fmaxf(hm[5], bfhi(u2));
  }

  float dal[NH];
  #pragma unroll
  for (int h = 0; h < NH; ++h)
    dal[h] = wave_sum64(hm[h] * att[h * 128 + 64 + lane]);

  float acc[NH], den[NH];
  #pragma unroll
  for (int h = 0; h < NH; ++h) acc[h] = 0.f;

  if (deg <= 64) {
    const bool act = lane < deg;
    int sE = 0;
    float4 sA = make_float4(0, 0, 0, 0), sB = sA;
    if (act) {
      sE = scsr[o0 + lane];
      const float4* sp = (const float4*)&sal[(long)sE * SALS];
      sA = sp[0]; sB = sp[1];
    }
    float svv[NH] = {sA.x, sA.y, sA.z, sA.w, sB.x, sB.y};
    float e6[NH];
    #pragma unroll
    for (int h = 0; h < NH; ++h) {
      float al = svv[h] + dal[h];
      al = (al >= 0.f) ? al : NEG_SLOPE * al;
      float a = act ? al : -INFINITY;
      float mx = wave_max64(a);
      e6[h] = act ? expf(a - mx) : 0.f;
      den[h] = wave_sum64(e6[h]);
    }
    #pragma unroll
    for (int idx = 0; idx < DCACHE; ++idx) {
      if (idx < deg) {
        float w0 = __shfl(e6[0], idx), w1 = __shfl(e6[1], idx);
        float w2 = __shfl(e6[2], idx), w3 = __shfl(e6[3], idx);
        float w4 = __shfl(e6[4], idx), w5 = __shfl(e6[5], idx);
        acc[0] = fmaf(bflo(ck0[idx]), w0, acc[0]);
        acc[1] = fmaf(bfhi(ck0[idx]), w1, acc[1]);
        acc[2] = fmaf(bflo(ck1[idx]), w2, acc[2]);
        acc[3] = fmaf(bfhi(ck1[idx]), w3, acc[3]);
        acc[4] = fmaf(bflo(ck2[idx]), w4, acc[4]);
        acc[5] = fmaf(bfhi(ck2[idx]), w5, acc[5]);
      }
    }
    for (int j = o0 + DCACHE; j < o1; ++j) {
      int ii = j - o0;
      long s = scsr[j];
      const unsigned* rp = &h2p[s * 192 + lane * 3];
      unsigned u0 = rp[0], u1 = rp[1], u2 = rp[2];
      float w0 = __shfl(e6[0], ii), w1 = __shfl(e6[1], ii);
      float w2 = __shfl(e6[2], ii), w3 = __shfl(e6[3], ii);
      float w4 = __shfl(e6[4], ii), w5 = __shfl(e6[5], ii);
      acc[0] = fmaf(bflo(u0), w0, acc[0]);
      acc[1] = fmaf(bfhi(u0), w1, acc[1]);
      acc[2] = fmaf(bflo(u1), w2, acc[2]);
      acc[3] = fmaf(bfhi(u1), w3, acc[3]);
      acc[4] = fmaf(bflo(u2), w4, acc[4]);
      acc[5] = fmaf(bfhi(u2), w5, acc[5]);
    }
  } else {
    float mx[NH];
    #pragma unroll
    for (int h = 0; h < NH; ++h) { mx[h] = -INFINITY; den[h] = 0.f; }
    for (int base = o0; base < o1; base += 64) {
      int j = base + lane;
      float a6[NH];
      if (j < o1) {
        long s = scsr[j];
        const float4* sp = (const float4*)&sal[s * SALS];
        float4 sA = sp[0], sB = sp[1];
        float svv[NH] = {sA.x, sA.y, sA.z, sA.w, sB.x, sB.y};
        #pragma unroll
        for (int h = 0; h < NH; ++h) {
          float al = svv[h] + dal[h];
          a6[h] = (al >= 0.f) ? al : NEG_SLOPE * al;
        }
      } else {
        #pragma unroll
        for (int h = 0; h < NH; ++h) a6[h] = -INFINITY;
      }
      #pragma unroll
      for (int h = 0; h < NH; ++h) mx[h] = fmaxf(mx[h], wave_max64(a6[h]));
    }
    for (int base = o0; base < o1; base += 64) {
      int cs = o1 - base; if (cs > 64) cs = 64;
      int j = base + lane;
      float e6[NH]; int s = 0;
      if (j < o1) {
        s = scsr[j];
        const float4* sp = (const float4*)&sal[(long)s * SALS];
        float4 sA = sp[0], sB = sp[1];
        float svv[NH] = {sA.x, sA.y, sA.z, sA.w, sB.x, sB.y};
        #pragma unroll
        for (int h = 0; h < NH; ++h) {
          float al = svv[h] + dal[h];
          al = (al >= 0.f) ? al : NEG_SLOPE * al;
          e6[h] = expf(al - mx[h]);
        }
      } else {
        #pragma unroll
        for (int h = 0; h < NH; ++h) e6[h] = 0.f;
      }
      #pragma unroll
      for (int h = 0; h < NH; ++h) den[h] += wave_sum64(e6[h]);
      for (int jj = 0; jj < cs; ++jj) {
        int sj = __shfl(s, jj);
        const unsigned* rp = &h2p[(long)sj * 192 + lane * 3];
        unsigned u0 = rp[0], u1 = rp[1], u2 = rp[2];
        float w0 = __shfl(e6[0], jj), w1 = __shfl(e6[1], jj);
        float w2 = __shfl(e6[2], jj), w3 = __shfl(e6[3], jj);
        float w4 = __shfl(e6[4], jj), w5 = __shfl(e6[5], jj);
        acc[0] = fmaf(bflo(u0), w0, acc[0]);
        acc[1] = fmaf(bfhi(u0), w1, acc[1]);
        acc[2] = fmaf(bflo(u1), w2, acc[2]);
        acc[3] = fmaf(bfhi(u1), w3, acc[3]);
        acc[4] = fmaf(bflo(u2), w4, acc[4]);
        acc[5] = fmaf(bfhi(u2), w5, acc[5]);
      }
    }
  }

  float o = 0.f;
  #pragma unroll
  for (int h = 0; h < NH; ++h) o += acc[h] / den[h];
  xm[(long)d * 64 + lane] = o * (1.0f / NH);
}

// fitness[d] = sigmoid(bsc[d] * sum_j dot(an[s_j], an[d]))
// wave per node, paired lanes: lanes 0-31 edge j, lanes 32-63 edge j+1,
// each lane handles a bf16 channel-pair (dword load).
__global__ __launch_bounds__(256)
void k_cosout(const int* __restrict__ soff, const int* __restrict__ scsr,
              const unsigned* __restrict__ an32, const float* __restrict__ bsc,
              float* __restrict__ out, int n) {
  const int lane = threadIdx.x & 63;
  const int p = lane & 31;
  const int hf = lane >> 5;
  const int d = blockIdx.x * 4 + (threadIdx.x >> 6);
  if (d >= n) return;
  const int o0 = soff[d], o1 = soff[d + 1];
  unsigned ud = an32[(long)d * 32 + p];
  float adx = bflo(ud), ady = bfhi(ud);
  float cl = 0.f;
  for (int j = o0; j < o1; j += 2) {
    int jj = j + hf;
    if (jj < o1) {
      long s = scsr[jj];
      unsigned u = an32[s * 32 + p];
      cl += adx * bflo(u) + ady * bfhi(u);
    }
  }
  float cs = wave_sum64(cl);
  if (lane == 0) out[d] = 1.0f / (1.0f + expf(-bsc[d] * cs));
}

// ---------- launcher ----------
static inline unsigned gsblocks(long total) {
  long b = (total + TPB - 1) / TPB;
  if (b > 131072) b = 131072;
  return (unsigned)b;
}

extern "C" void kernel_launch(void* const* d_in, const int* in_sizes, int n_in,
                              void* d_out, int out_size, void* d_ws, size_t ws_size,
                              hipStream_t stream) {
  const float* x   = (const float*)d_in[0];
  const float* Wg  = (const float*)d_in[1];
  const float* bg  = (const float*)d_in[2];
  const float* Wt  = (const float*)d_in[3];
  const float* att = (const float*)d_in[4];
  const float* W1  = (const float*)d_in[5];
  const float* W2  = (const float*)d_in[6];
  const float* b2  = (const float*)d_in[7];
  const int* src   = (const int*)d_in[8];
  const int* dst   = (const int*)d_in[9];
  const int* ssrc  = (const int*)d_in[10];
  const int* sdst  = (const int*)d_in[11];

  const long n   = in_sizes[0] / 64;   // 50000
  const long en  = in_sizes[8];        // E + N
  const long sen = in_sizes[10];       // N + E
  const int  nb  = (int)((n + 2047) / 2048);

  char* base = (char*)d_ws;
  size_t off = 0;
  auto alloc = [&](size_t bytes) -> void* {
    void* p = base + off;
    off += (bytes + 255) & ~(size_t)255;
    return p;
  };
  int*   gcnt = (int*)alloc(n * 4);
  int*   scnt = (int*)alloc(n * 4);   // contiguous with gcnt (one memset)
  int*   goff = (int*)alloc((n + 1) * 4);
  int*   soff = (int*)alloc((n + 1) * 4);
  int*   gcur = (int*)alloc(n * 4);
  int*   scur = (int*)alloc(n * 4);
  int*   gcsr = (int*)alloc(en * 4);
  int*   scsr = (int*)alloc(sen * 4);
  int*   bsum = (int*)alloc(2 * (size_t)nb * 4);
  float* dinv = (float*)alloc(n * 4);
  unsigned* xb = (unsigned*)alloc(n * 32 * 4);        // prescaled bf16 x pairs
  float* h    = (float*)alloc(n * 64 * 4);            // xagg, later xm
  float* xpj  = (float*)alloc(n * 64 * 4);            // later anorm (bf16)
  unsigned* h2p = (unsigned*)alloc(n * 192 * 4);      // channel-major bf16 pairs
  float* sal  = (float*)alloc(n * SALS * 4);
  float* bsc  = (float*)alloc(n * 4);
  float* xagg = h;                                    // alias
  float* xm   = h;                                    // alias (xagg dead after GEMM)
  unsigned short* anorm = (unsigned short*)xpj;       // alias
  float* out  = (float*)d_out;

  const unsigned rowblk  = (unsigned)((n + 63) / 64);
  const unsigned nodeblk = (unsigned)((n + 3) / 4);

  // ---- CSR build (both graphs) + dinv ----
  hipMemsetAsync(gcnt, 0, (size_t)((char*)scnt - (char*)gcnt) + n * 4, stream);
  k_cnt<<<gsblocks((en + 1) / 2), TPB, 0, stream>>>(dst, sdst, gcnt, scnt, en, sen);
  k_scanA<<<2 * nb, 1024, 0, stream>>>(gcnt, scnt, bsum, dinv, (int)n, nb);
  k_scanB<<<1, 64, 0, stream>>>(bsum, nb);
  k_scanC<<<2 * nb, 1024, 0, stream>>>(gcnt, goff, gcur, scnt, soff, scur,
                                       bsum, (int)n, nb);
  k_scatter<<<gsblocks((en + 1) / 2), TPB, 0, stream>>>(src, dst, ssrc, sdst,
                                              gcur, gcsr, scur, scsr, en, sen);

  // ---- prescaled bf16 x ----
  k_xprep<<<gsblocks(n * 32), TPB, 0, stream>>>(x, dinv, xb, n);

  // ---- GCN aggregation on x (commuted with weight multiply) ----
  k_gcn2<<<nodeblk, 256, 0, stream>>>(goff, gcsr, xb, x, dinv, xagg, (int)n);

  // ---- xpj = xagg @ W_gcn + bg ----
  { dim3 g(rowblk, 1);
    k_gemm64v3<0><<<g, 256, 0, stream>>>(xagg, Wg, xpj, nullptr, bg,
                                         nullptr, nullptr, nullptr, (int)n, 64); }

  // ---- h2 = xpj @ weight (bf16 channel-major packed) + fused sal ----
  k_gemm_h2<<<rowblk, 256, 0, stream>>>(xpj, Wt, h2p, att, sal, (int)n);

  // ---- fused attention -> xm ----
  k_mega<<<nodeblk, 256, 0, stream>>>(soff, scsr, h2p, sal, att, xm, (int)n);

  // ---- a = normalize(xm @ W1) (bf16) + bsc, fused epilogue ----
  { dim3 g(rowblk, 1);
    k_gemm64v3<2><<<g, 256, 0, stream>>>(xm, W1, nullptr, anorm, nullptr,
                                         W2, b2, bsc, (int)n, 64); }

  // ---- cosine + sigmoid -> out ----
  k_cosout<<<nodeblk, 256, 0, stream>>>(soff, scsr, (const unsigned*)anorm,
                                        bsc, out, (int)n);
}

// Round 10
// 424.959 us; speedup vs baseline: 1.0064x; 1.0064x over previous
//
#include <hip/hip_runtime.h>
#include <math.h>

#define TPB 256
#define NEG_SLOPE 0.2f
#define COS_EPS 1e-8f
#define NH 6
#define GSTRIDE 68   // LDS row stride (floats) for GEMM tiles
#define DCACHE 12    // neighbor rows cached in registers per node
#define SALS 8       // sal row stride (floats), 32B-aligned

// ---------- helpers ----------
__device__ inline float wave_sum64(float v) {
  #pragma unroll
  for (int off = 32; off > 0; off >>= 1) v += __shfl_down(v, off);
  return __shfl(v, 0);
}
__device__ inline float wave_max64(float v) {
  #pragma unroll
  for (int off = 32; off > 0; off >>= 1) v = fmaxf(v, __shfl_down(v, off));
  return __shfl(v, 0);
}
__device__ inline unsigned short f2bf(float f) {
  unsigned u = __float_as_uint(f);
  unsigned r = (u + 0x7fffu + ((u >> 16) & 1u)) >> 16;   // RNE
  return (unsigned short)r;
}
__device__ inline float bf2f(unsigned short b) {
  return __uint_as_float(((unsigned)b) << 16);
}
__device__ inline unsigned packbf(float lo, float hi) {
  return (unsigned)f2bf(lo) | ((unsigned)f2bf(hi) << 16);
}
__device__ inline float bflo(unsigned u) { return __uint_as_float(u << 16); }
__device__ inline float bfhi(unsigned u) { return __uint_as_float(u & 0xffff0000u); }

#define GS_LOOP(i, total) \
  for (long i = (long)blockIdx.x * blockDim.x + threadIdx.x; i < (total); \
       i += (long)gridDim.x * blockDim.x)

// ---------- CSR build ----------
__global__ void k_cnt(const int* __restrict__ dst, const int* __restrict__ sdst,
                      int* __restrict__ gcnt, int* __restrict__ scnt,
                      long en, long sen) {
  long mx = en > sen ? en : sen;
  GS_LOOP(e, mx) {
    if (e < en)  atomicAdd(&gcnt[dst[e]], 1);
    if (e < sen) atomicAdd(&scnt[sdst[e]], 1);
  }
}

// phase A: per-tile sums (2048 elems/block) + dinv (g-array blocks only)
__global__ __launch_bounds__(1024)
void k_scanA(const int* __restrict__ gcnt, const int* __restrict__ scnt,
             int* __restrict__ bsum, float* __restrict__ dinv, int n, int nb) {
  const int b = blockIdx.x;
  const bool isS = b >= nb;
  const int tb = isS ? b - nb : b;
  const int* cnt = isS ? scnt : gcnt;
  const int t = threadIdx.x;
  const int i0 = tb * 2048 + 2 * t;
  int v0 = (i0 < n) ? cnt[i0] : 0;
  int v1 = (i0 + 1 < n) ? cnt[i0 + 1] : 0;
  if (!isS) {
    if (i0 < n)     dinv[i0]     = rsqrtf((float)v0 + 1.0f);
    if (i0 + 1 < n) dinv[i0 + 1] = rsqrtf((float)v1 + 1.0f);
  }
  __shared__ int red[16];
  int x = v0 + v1;
  #pragma unroll
  for (int o = 32; o > 0; o >>= 1) x += __shfl_down(x, o);
  const int lane = t & 63, wv = t >> 6;
  if (lane == 0) red[wv] = x;
  __syncthreads();
  if (t < 64) {
    int w = (t < 16) ? red[t] : 0;
    #pragma unroll
    for (int o = 32; o > 0; o >>= 1) w += __shfl_down(w, o);
    if (t == 0) bsum[b] = w;
  }
}

// phase B: exclusive-scan the two halves of bsum (nb each)
__global__ void k_scanB(int* __restrict__ bsum, int nb) {
  const int lane = threadIdx.x;   // 64 threads
  if (nb <= 32) {
    int half = lane >> 5, idx = lane & 31;
    int base = half * nb;
    int v = (idx < nb) ? bsum[base + idx] : 0;
    int orig = v;
    #pragma unroll
    for (int d2 = 1; d2 < 32; d2 <<= 1) {
      int y = __shfl_up(v, d2, 32);
      if (idx >= d2) v += y;
    }
    if (idx < nb) bsum[base + idx] = v - orig;
  } else if (lane == 0) {
    int run = 0;
    for (int i = 0; i < nb; ++i) { int v = bsum[i]; bsum[i] = run; run += v; }
    run = 0;
    for (int i = 0; i < nb; ++i) { int v = bsum[nb + i]; bsum[nb + i] = run; run += v; }
  }
}

// phase C: per-tile scan + writeback of off/cur
__global__ __launch_bounds__(1024)
void k_scanC(const int* __restrict__ gcnt, int* __restrict__ goff, int* __restrict__ gcur,
             const int* __restrict__ scnt, int* __restrict__ soff, int* __restrict__ scur,
             const int* __restrict__ bsum, int n, int nb) {
  const int b = blockIdx.x;
  const bool isS = b >= nb;
  const int tb = isS ? b - nb : b;
  const int* cnt = isS ? scnt : gcnt;
  int* off = isS ? soff : goff;
  int* cur = isS ? scur : gcur;
  const int t = threadIdx.x;
  const int i0 = tb * 2048 + 2 * t;
  int v0 = (i0 < n) ? cnt[i0] : 0;
  int v1 = (i0 + 1 < n) ? cnt[i0 + 1] : 0;
  int s2 = v0 + v1;
  const int lane = t & 63, wv = t >> 6;
  int x = s2;
  #pragma unroll
  for (int d2 = 1; d2 < 64; d2 <<= 1) {
    int y = __shfl_up(x, d2);
    if (lane >= d2) x += y;
  }
  __shared__ int wsum[16];
  if (lane == 63) wsum[wv] = x;
  __syncthreads();
  if (t < 64) {
    int w = (t < 16) ? wsum[t] : 0;
    #pragma unroll
    for (int d2 = 1; d2 < 16; d2 <<= 1) {
      int y = __shfl_up(w, d2);
      if ((int)t >= d2) w += y;
    }
    if (t < 16) wsum[t] = w;
  }
  __syncthreads();
  int ex = x - s2 + (wv ? wsum[wv - 1] : 0) + bsum[b];
  if (i0 < n)     { cur[i0] = ex;          off[i0 + 1] = ex + v0; }
  if (i0 + 1 < n) { cur[i0 + 1] = ex + v0; off[i0 + 2] = ex + v0 + v1; }
  if (i0 == 0) off[0] = 0;
}

__global__ void k_scatter(const int* __restrict__ src, const int* __restrict__ dst,
                          const int* __restrict__ ssrc, const int* __restrict__ sdst,
                          int* __restrict__ gcur, int* __restrict__ gcsr,
                          int* __restrict__ scur, int* __restrict__ scsr,
                          long en, long sen) {
  long mx = en > sen ? en : sen;
  GS_LOOP(e, mx) {
    if (e < en)  { int d = dst[e];  int p = atomicAdd(&gcur[d], 1); gcsr[p] = src[e]; }
    if (e < sen) { int d = sdst[e]; int p = atomicAdd(&scur[d], 1); scsr[p] = ssrc[e]; }
  }
}

// ---------- GEMM: A[n][64] @ W[64][Mtot], 64x64 tile, 4x4 reg tile ----------
// MODE 0: fp32 out32; if rowscale != null, out *= rowscale[row] (dinv prescale).
// MODE 2: normalized bf16 rows (out16[r*64+c]) + bsc[r] = A_row·W2 + b2.
template <int MODE>
__global__ __launch_bounds__(256)
void k_gemm64v3(const float* __restrict__ A, const float* __restrict__ W,
                float* __restrict__ out32, unsigned short* __restrict__ out16,
                const float* __restrict__ rowscale,
                const float* __restrict__ W2, const float* __restrict__ b2,
                float* __restrict__ bsc, int n, int Mtot) {
  __shared__ float At[64 * GSTRIDE];
  __shared__ float Wl[64 * GSTRIDE];
  const int t  = threadIdx.x;
  const int tx = t & 15;
  const int ty = t >> 4;
  const int col0 = blockIdx.y * 64;
  const long row0 = (long)blockIdx.x * 64;

  #pragma unroll
  for (int i = 0; i < 4; ++i) {
    int k = ty + 16 * i;
    float4 wv = *(const float4*)&W[(long)k * Mtot + col0 + 4 * tx];
    *(float4*)&Wl[k * GSTRIDE + 4 * tx] = wv;
  }
  #pragma unroll
  for (int i = 0; i < 4; ++i) {
    int r = ty + 16 * i;
    long gr = row0 + r; if (gr >= n) gr = n - 1;
    float4 av = *(const float4*)&A[gr * 64 + 4 * tx];
    At[(4 * tx + 0) * GSTRIDE + r] = av.x;
    At[(4 * tx + 1) * GSTRIDE + r] = av.y;
    At[(4 * tx + 2) * GSTRIDE + r] = av.z;
    At[(4 * tx + 3) * GSTRIDE + r] = av.w;
  }
  __syncthreads();

  const int c0 = 4 * tx;
  const int r0 = 4 * ty;
  float acc[4][4] = {};
  #pragma unroll
  for (int k = 0; k < 64; ++k) {
    float4 av = *(const float4*)&At[k * GSTRIDE + r0];
    float4 wv = *(const float4*)&Wl[k * GSTRIDE + c0];
    acc[0][0] = fmaf(av.x, wv.x, acc[0][0]); acc[0][1] = fmaf(av.x, wv.y, acc[0][1]);
    acc[0][2] = fmaf(av.x, wv.z, acc[0][2]); acc[0][3] = fmaf(av.x, wv.w, acc[0][3]);
    acc[1][0] = fmaf(av.y, wv.x, acc[1][0]); acc[1][1] = fmaf(av.y, wv.y, acc[1][1]);
    acc[1][2] = fmaf(av.y, wv.z, acc[1][2]); acc[1][3] = fmaf(av.y, wv.w, acc[1][3]);
    acc[2][0] = fmaf(av.z, wv.x, acc[2][0]); acc[2][1] = fmaf(av.z, wv.y, acc[2][1]);
    acc[2][2] = fmaf(av.z, wv.z, acc[2][2]); acc[2][3] = fmaf(av.z, wv.w, acc[2][3]);
    acc[3][0] = fmaf(av.w, wv.x, acc[3][0]); acc[3][1] = fmaf(av.w, wv.y, acc[3][1]);
    acc[3][2] = fmaf(av.w, wv.z, acc[3][2]); acc[3][3] = fmaf(av.w, wv.w, acc[3][3]);
  }

  if constexpr (MODE == 0) {
    #pragma unroll
    for (int i = 0; i < 4; ++i) {
      long gr = row0 + r0 + i;
      if (gr < n) {
        float sc = rowscale ? rowscale[gr] : 1.0f;
        *(float4*)&out32[gr * Mtot + col0 + c0] =
          make_float4(acc[i][0] * sc, acc[i][1] * sc, acc[i][2] * sc, acc[i][3] * sc);
      }
    }
  }
  if constexpr (MODE == 2) {
    float p[4], q[4];
    #pragma unroll
    for (int i = 0; i < 4; ++i) {
      q[i] = acc[i][0]*acc[i][0] + acc[i][1]*acc[i][1] +
             acc[i][2]*acc[i][2] + acc[i][3]*acc[i][3];
      p[i] = At[(c0+0) * GSTRIDE + r0 + i] * W2[c0+0] +
             At[(c0+1) * GSTRIDE + r0 + i] * W2[c0+1] +
             At[(c0+2) * GSTRIDE + r0 + i] * W2[c0+2] +
             At[(c0+3) * GSTRIDE + r0 + i] * W2[c0+3];
    }
    #pragma unroll
    for (int m = 1; m < 16; m <<= 1) {
      #pragma unroll
      for (int i = 0; i < 4; ++i) { p[i] += __shfl_xor(p[i], m); q[i] += __shfl_xor(q[i], m); }
    }
    float bb = b2[0];
    #pragma unroll
    for (int i = 0; i < 4; ++i) {
      long gr = row0 + r0 + i;
      if (gr < n) {
        float rn = 1.0f / fmaxf(sqrtf(q[i]), COS_EPS);
        ushort4 v;
        v.x = f2bf(acc[i][0] * rn); v.y = f2bf(acc[i][1] * rn);
        v.z = f2bf(acc[i][2] * rn); v.w = f2bf(acc[i][3] * rn);
        *(ushort4*)&out16[gr * 64 + c0] = v;
        if (tx == 0) bsc[gr] = p[i] + bb;
      }
    }
  }
}

// ---------- h2 GEMM: all 384 cols (6 heads) per block, packed channel-major out.
__global__ __launch_bounds__(256)
void k_gemm_h2(const float* __restrict__ A, const float* __restrict__ W,
               unsigned* __restrict__ h2p, const float* __restrict__ att,
               float* __restrict__ sal, int n) {
  __shared__ float At[64 * GSTRIDE];
  __shared__ float Wl[64 * GSTRIDE];
  const int t  = threadIdx.x;
  const int tx = t & 15;
  const int ty = t >> 4;
  const long row0 = (long)blockIdx.x * 64;
  const int c0 = 4 * tx;
  const int r0 = 4 * ty;

  #pragma unroll
  for (int i = 0; i < 4; ++i) {
    int r = ty + 16 * i;
    long gr = row0 + r; if (gr >= n) gr = n - 1;
    float4 av = *(const float4*)&A[gr * 64 + 4 * tx];
    At[(4 * tx + 0) * GSTRIDE + r] = av.x;
    At[(4 * tx + 1) * GSTRIDE + r] = av.y;
    At[(4 * tx + 2) * GSTRIDE + r] = av.z;
    At[(4 * tx + 3) * GSTRIDE + r] = av.w;
  }
  float4 wr[4];
  #pragma unroll
  for (int i = 0; i < 4; ++i)
    wr[i] = *(const float4*)&W[(long)(ty + 16 * i) * 384 + 4 * tx];

  float4 acc[6][4];
  #pragma unroll
  for (int h = 0; h < 6; ++h)
    #pragma unroll
    for (int i = 0; i < 4; ++i) acc[h][i] = make_float4(0.f, 0.f, 0.f, 0.f);

  #pragma unroll
  for (int head = 0; head < 6; ++head) {
    #pragma unroll
    for (int i = 0; i < 4; ++i)
      *(float4*)&Wl[(ty + 16 * i) * GSTRIDE + 4 * tx] = wr[i];
    __syncthreads();
    if (head < 5) {
      #pragma unroll
      for (int i = 0; i < 4; ++i)
        wr[i] = *(const float4*)&W[(long)(ty + 16 * i) * 384 + (head + 1) * 64 + 4 * tx];
    }
    #pragma unroll 16
    for (int k = 0; k < 64; ++k) {
      float4 av = *(const float4*)&At[k * GSTRIDE + r0];
      float4 wv = *(const float4*)&Wl[k * GSTRIDE + c0];
      acc[head][0].x = fmaf(av.x, wv.x, acc[head][0].x);
      acc[head][0].y = fmaf(av.x, wv.y, acc[head][0].y);
      acc[head][0].z = fmaf(av.x, wv.z, acc[head][0].z);
      acc[head][0].w = fmaf(av.x, wv.w, acc[head][0].w);
      acc[head][1].x = fmaf(av.y, wv.x, acc[head][1].x);
      acc[head][1].y = fmaf(av.y, wv.y, acc[head][1].y);
      acc[head][1].z = fmaf(av.y, wv.z, acc[head][1].z);
      acc[head][1].w = fmaf(av.y, wv.w, acc[head][1].w);
      acc[head][2].x = fmaf(av.z, wv.x, acc[head][2].x);
      acc[head][2].y = fmaf(av.z, wv.y, acc[head][2].y);
      acc[head][2].z = fmaf(av.z, wv.z, acc[head][2].z);
      acc[head][2].w = fmaf(av.z, wv.w, acc[head][2].w);
      acc[head][3].x = fmaf(av.w, wv.x, acc[head][3].x);
      acc[head][3].y = fmaf(av.w, wv.y, acc[head][3].y);
      acc[head][3].z = fmaf(av.w, wv.z, acc[head][3].z);
      acc[head][3].w = fmaf(av.w, wv.w, acc[head][3].w);
    }
    __syncthreads();
  }

  #pragma unroll
  for (int i = 0; i < 4; ++i) {
    long gr = row0 + r0 + i;
    if (gr < n) {
      uint4 u0, u1, u2;
      u0.x = packbf(acc[0][i].x, acc[1][i].x);
      u0.y = packbf(acc[2][i].x, acc[3][i].x);
      u0.z = packbf(acc[4][i].x, acc[5][i].x);
      u0.w = packbf(acc[0][i].y, acc[1][i].y);
      u1.x = packbf(acc[2][i].y, acc[3][i].y);
      u1.y = packbf(acc[4][i].y, acc[5][i].y);
      u1.z = packbf(acc[0][i].z, acc[1][i].z);
      u1.w = packbf(acc[2][i].z, acc[3][i].z);
      u2.x = packbf(acc[4][i].z, acc[5][i].z);
      u2.y = packbf(acc[0][i].w, acc[1][i].w);
      u2.z = packbf(acc[2][i].w, acc[3][i].w);
      u2.w = packbf(acc[4][i].w, acc[5][i].w);
      unsigned* dstp = &h2p[gr * 192 + c0 * 3];
      *(uint4*)(dstp + 0) = u0;
      *(uint4*)(dstp + 4) = u1;
      *(uint4*)(dstp + 8) = u2;
    }
  }
  #pragma unroll
  for (int head = 0; head < 6; ++head) {
    float a0 = att[head * 128 + c0 + 0], a1 = att[head * 128 + c0 + 1];
    float a2 = att[head * 128 + c0 + 2], a3 = att[head * 128 + c0 + 3];
    float p[4];
    #pragma unroll
    for (int i = 0; i < 4; ++i)
      p[i] = acc[head][i].x * a0 + acc[head][i].y * a1 +
             acc[head][i].z * a2 + acc[head][i].w * a3;
    #pragma unroll
    for (int m = 1; m < 16; m <<= 1) {
      #pragma unroll
      for (int i = 0; i < 4; ++i) p[i] += __shfl_xor(p[i], m);
    }
    if (tx == 0) {
      #pragma unroll
      for (int i = 0; i < 4; ++i) {
        long gr = row0 + r0 + i;
        if (gr < n) sal[gr * SALS + head] = p[i];
      }
    }
  }
}

// ---------- GCN aggregate via CSR (wave per node, lane = channel) ----------
// hs = (x@Wg) prescaled by dinv[row]. acc = hs[d] + sum_s hs[s]; xpj = bg + dinv[d]*acc
__global__ __launch_bounds__(256)
void k_gcn_csr(const int* __restrict__ goff, const int* __restrict__ gcsr,
               const float* __restrict__ hs, const float* __restrict__ dinv,
               const float* __restrict__ bg, float* __restrict__ xpj, int n) {
  const int lane = threadIdx.x & 63;
  const int d = blockIdx.x * 4 + (threadIdx.x >> 6);
  if (d >= n) return;
  const int o0 = goff[d], o1 = goff[d + 1];
  float acc = hs[(long)d * 64 + lane];   // self-loop term (already * dinv[d])
  int j = o0;
  for (; j + 1 < o1; j += 2) {
    int s0 = gcsr[j], s1 = gcsr[j + 1];
    acc += hs[(long)s0 * 64 + lane];
    acc += hs[(long)s1 * 64 + lane];
  }
  if (j < o1) acc += hs[(long)gcsr[j] * 64 + lane];
  xpj[(long)d * 64 + lane] = bg[lane] + dinv[d] * acc;
}

// ---------- fused attention mega-kernel (wave per node) ----------
__global__ __launch_bounds__(256)
void k_mega(const int* __restrict__ soff, const int* __restrict__ scsr,
            const unsigned* __restrict__ h2p, const float* __restrict__ sal,
            const float* __restrict__ att, float* __restrict__ xm, int n) {
  const int lane = threadIdx.x & 63;
  const int d = blockIdx.x * 4 + (threadIdx.x >> 6);
  if (d >= n) return;
  const int o0 = soff[d], o1 = soff[d + 1];
  const int deg = o1 - o0;

  unsigned ck0[DCACHE], ck1[DCACHE], ck2[DCACHE];
  float hm[NH];
  #pragma unroll
  for (int h = 0; h < NH; ++h) hm[h] = -INFINITY;
  #pragma unroll
  for (int idx = 0; idx < DCACHE; ++idx) {
    unsigned u0 = 0, u1 = 0, u2 = 0;
    if (idx < deg) {
      long s = scsr[o0 + idx];
      const unsigned* rp = &h2p[s * 192 + lane * 3];
      u0 = rp[0]; u1 = rp[1]; u2 = rp[2];
      hm[0] = fmaxf(hm[0], bflo(u0)); hm[1] = fmaxf(hm[1], bfhi(u0));
      hm[2] = fmaxf(hm[2], bflo(u1)); hm[3] = fmaxf(hm[3], bfhi(u1));
      hm[4] = fmaxf(hm[4], bflo(u2)); hm[5] = fmaxf(hm[5], bfhi(u2));
    }
    ck0[idx] = u0; ck1[idx] = u1; ck2[idx] = u2;
  }
  for (int j = o0 + DCACHE; j < o1; ++j) {
    long s = scsr[j];
    const unsigned* rp = &h2p[s * 192 + lane * 3];
    unsigned u0 = rp[0], u1 = rp[1], u2 = rp[2];
    hm[0] = fmaxf(hm[0], bflo(u0)); hm[1] = fmaxf(hm[1], bfhi(u0));
    hm[2] = fmaxf(hm[2], bflo(u1)); hm[3] = fmaxf(hm[3], bfhi(u1));
    hm[4] = fmaxf(hm[4], bflo(u2)); hm[5] = fmaxf(hm[5], bfhi(u2));
  }

  float dal[NH];
  #pragma unroll
  for (int h = 0; h < NH; ++h)
    dal[h] = wave_sum64(hm[h] * att[h * 128 + 64 + lane]);

  float acc[NH], den[NH];
  #pragma unroll
  for (int h = 0; h < NH; ++h) acc[h] = 0.f;

  if (deg <= 64) {
    const bool act = lane < deg;
    int sE = 0;
    float4 sA = make_float4(0, 0, 0, 0), sB = sA;
    if (act) {
      sE = scsr[o0 + lane];
      const float4* sp = (const float4*)&sal[(long)sE * SALS];
      sA = sp[0]; sB = sp[1];
    }
    float svv[NH] = {sA.x, sA.y, sA.z, sA.w, sB.x, sB.y};
    float e6[NH];
    #pragma unroll
    for (int h = 0; h < NH; ++h) {
      float al = svv[h] + dal[h];
      al = (al >= 0.f) ? al : NEG_SLOPE * al;
      float a = act ? al : -INFINITY;
      float mx = wave_max64(a);
      e6[h] = act ? expf(a - mx) : 0.f;
      den[h] = wave_sum64(e6[h]);
    }
    #pragma unroll
    for (int idx = 0; idx < DCACHE; ++idx) {
      if (idx < deg) {
        float w0 = __shfl(e6[0], idx), w1 = __shfl(e6[1], idx);
        float w2 = __shfl(e6[2], idx), w3 = __shfl(e6[3], idx);
        float w4 = __shfl(e6[4], idx), w5 = __shfl(e6[5], idx);
        acc[0] = fmaf(bflo(ck0[idx]), w0, acc[0]);
        acc[1] = fmaf(bfhi(ck0[idx]), w1, acc[1]);
        acc[2] = fmaf(bflo(ck1[idx]), w2, acc[2]);
        acc[3] = fmaf(bfhi(ck1[idx]), w3, acc[3]);
        acc[4] = fmaf(bflo(ck2[idx]), w4, acc[4]);
        acc[5] = fmaf(bfhi(ck2[idx]), w5, acc[5]);
      }
    }
    for (int j = o0 + DCACHE; j < o1; ++j) {
      int ii = j - o0;
      long s = scsr[j];
      const unsigned* rp = &h2p[s * 192 + lane * 3];
      unsigned u0 = rp[0], u1 = rp[1], u2 = rp[2];
      float w0 = __shfl(e6[0], ii), w1 = __shfl(e6[1], ii);
      float w2 = __shfl(e6[2], ii), w3 = __shfl(e6[3], ii);
      float w4 = __shfl(e6[4], ii), w5 = __shfl(e6[5], ii);
      acc[0] = fmaf(bflo(u0), w0, acc[0]);
      acc[1] = fmaf(bfhi(u0), w1, acc[1]);
      acc[2] = fmaf(bflo(u1), w2, acc[2]);
      acc[3] = fmaf(bfhi(u1), w3, acc[3]);
      acc[4] = fmaf(bflo(u2), w4, acc[4]);
      acc[5] = fmaf(bfhi(u2), w5, acc[5]);
    }
  } else {
    float mx[NH];
    #pragma unroll
    for (int h = 0; h < NH; ++h) { mx[h] = -INFINITY; den[h] = 0.f; }
    for (int base = o0; base < o1; base += 64) {
      int j = base + lane;
      float a6[NH];
      if (j < o1) {
        long s = scsr[j];
        const float4* sp = (const float4*)&sal[s * SALS];
        float4 sA = sp[0], sB = sp[1];
        float svv[NH] = {sA.x, sA.y, sA.z, sA.w, sB.x, sB.y};
        #pragma unroll
        for (int h = 0; h < NH; ++h) {
          float al = svv[h] + dal[h];
          a6[h] = (al >= 0.f) ? al : NEG_SLOPE * al;
        }
      } else {
        #pragma unroll
        for (int h = 0; h < NH; ++h) a6[h] = -INFINITY;
      }
      #pragma unroll
      for (int h = 0; h < NH; ++h) mx[h] = fmaxf(mx[h], wave_max64(a6[h]));
    }
    for (int base = o0; base < o1; base += 64) {
      int cs = o1 - base; if (cs > 64) cs = 64;
      int j = base + lane;
      float e6[NH]; int s = 0;
      if (j < o1) {
        s = scsr[j];
        const float4* sp = (const float4*)&sal[(long)s * SALS];
        float4 sA = sp[0], sB = sp[1];
        float svv[NH] = {sA.x, sA.y, sA.z, sA.w, sB.x, sB.y};
        #pragma unroll
        for (int h = 0; h < NH; ++h) {
          float al = svv[h] + dal[h];
          al = (al >= 0.f) ? al : NEG_SLOPE * al;
          e6[h] = expf(al - mx[h]);
        }
      } else {
        #pragma unroll
        for (int h = 0; h < NH; ++h) e6[h] = 0.f;
      }
      #pragma unroll
      for (int h = 0; h < NH; ++h) den[h] += wave_sum64(e6[h]);
      for (int jj = 0; jj < cs; ++jj) {
        int sj = __shfl(s, jj);
        const unsigned* rp = &h2p[(long)sj * 192 + lane * 3];
        unsigned u0 = rp[0], u1 = rp[1], u2 = rp[2];
        float w0 = __shfl(e6[0], jj), w1 = __shfl(e6[1], jj);
        float w2 = __shfl(e6[2], jj), w3 = __shfl(e6[3], jj);
        float w4 = __shfl(e6[4], jj), w5 = __shfl(e6[5], jj);
        acc[0] = fmaf(bflo(u0), w0, acc[0]);
        acc[1] = fmaf(bfhi(u0), w1, acc[1]);
        acc[2] = fmaf(bflo(u1), w2, acc[2]);
        acc[3] = fmaf(bfhi(u1), w3, acc[3]);
        acc[4] = fmaf(bflo(u2), w4, acc[4]);
        acc[5] = fmaf(bfhi(u2), w5, acc[5]);
      }
    }
  }

  float o = 0.f;
  #pragma unroll
  for (int h = 0; h < NH; ++h) o += acc[h] / den[h];
  xm[(long)d * 64 + lane] = o * (1.0f / NH);
}

// fitness[d] = sigmoid(bsc[d] * sum_j dot(an[s_j], an[d]))  (wave per node, bf16 an)
__global__ __launch_bounds__(256)
void k_cosout(const int* __restrict__ soff, const int* __restrict__ scsr,
              const unsigned short* __restrict__ an, const float* __restrict__ bsc,
              float* __restrict__ out, int n) {
  const int lane = threadIdx.x & 63;
  const int d = blockIdx.x * 4 + (threadIdx.x >> 6);
  if (d >= n) return;
  const int o0 = soff[d], o1 = soff[d + 1];
  float ad = bf2f(an[(long)d * 64 + lane]);
  float cl = 0.f;
  int j = o0;
  for (; j + 1 < o1; j += 2) {
    int s0 = scsr[j], s1 = scsr[j + 1];
    float f0 = bf2f(an[(long)s0 * 64 + lane]);
    float f1 = bf2f(an[(long)s1 * 64 + lane]);
    cl = fmaf(ad, f0, cl);
    cl = fmaf(ad, f1, cl);
  }
  if (j < o1) { int s0 = scsr[j]; cl = fmaf(ad, bf2f(an[(long)s0 * 64 + lane]), cl); }
  float cs = wave_sum64(cl);
  if (lane == 0) out[d] = 1.0f / (1.0f + expf(-bsc[d] * cs));
}

// ---------- launcher ----------
static inline unsigned gsblocks(long total) {
  long b = (total + TPB - 1) / TPB;
  if (b > 131072) b = 131072;
  return (unsigned)b;
}

extern "C" void kernel_launch(void* const* d_in, const int* in_sizes, int n_in,
                              void* d_out, int out_size, void* d_ws, size_t ws_size,
                              hipStream_t stream) {
  const float* x   = (const float*)d_in[0];
  const float* Wg  = (const float*)d_in[1];
  const float* bg  = (const float*)d_in[2];
  const float* Wt  = (const float*)d_in[3];
  const float* att = (const float*)d_in[4];
  const float* W1  = (const float*)d_in[5];
  const float* W2  = (const float*)d_in[6];
  const float* b2  = (const float*)d_in[7];
  const int* src   = (const int*)d_in[8];
  const int* dst   = (const int*)d_in[9];
  const int* ssrc  = (const int*)d_in[10];
  const int* sdst  = (const int*)d_in[11];

  const long n   = in_sizes[0] / 64;   // 50000
  const long en  = in_sizes[8];        // E + N
  const long sen = in_sizes[10];       // N + E
  const int  nb  = (int)((n + 2047) / 2048);

  char* base = (char*)d_ws;
  size_t off = 0;
  auto alloc = [&](size_t bytes) -> void* {
    void* p = base + off;
    off += (bytes + 255) & ~(size_t)255;
    return p;
  };
  int*   gcnt = (int*)alloc(n * 4);
  int*   scnt = (int*)alloc(n * 4);   // contiguous with gcnt (one memset)
  int*   goff = (int*)alloc((n + 1) * 4);
  int*   soff = (int*)alloc((n + 1) * 4);
  int*   gcur = (int*)alloc(n * 4);
  int*   scur = (int*)alloc(n * 4);
  int*   gcsr = (int*)alloc(en * 4);
  int*   scsr = (int*)alloc(sen * 4);
  int*   bsum = (int*)alloc(2 * (size_t)nb * 4);
  float* dinv = (float*)alloc(n * 4);
  float* h    = (float*)alloc(n * 64 * 4);            // hs (prescaled), later xm
  float* xpj  = (float*)alloc(n * 64 * 4);            // later anorm (bf16)
  unsigned* h2p = (unsigned*)alloc(n * 192 * 4);      // channel-major bf16 pairs
  float* sal  = (float*)alloc(n * SALS * 4);
  float* bsc  = (float*)alloc(n * 4);
  float* hs   = h;                                    // alias
  float* xm   = h;                                    // alias (hs dead after gcn)
  unsigned short* anorm = (unsigned short*)xpj;       // alias
  float* out  = (float*)d_out;

  const unsigned rowblk  = (unsigned)((n + 63) / 64);
  const unsigned nodeblk = (unsigned)((n + 3) / 4);

  // ---- CSR build (both graphs) + dinv ----
  hipMemsetAsync(gcnt, 0, (size_t)((char*)scnt - (char*)gcnt) + n * 4, stream);
  k_cnt<<<gsblocks(en), TPB, 0, stream>>>(dst, sdst, gcnt, scnt, en, sen);
  k_scanA<<<2 * nb, 1024, 0, stream>>>(gcnt, scnt, bsum, dinv, (int)n, nb);
  k_scanB<<<1, 64, 0, stream>>>(bsum, nb);
  k_scanC<<<2 * nb, 1024, 0, stream>>>(gcnt, goff, gcur, scnt, soff, scur,
                                       bsum, (int)n, nb);
  k_scatter<<<gsblocks(en), TPB, 0, stream>>>(src, dst, ssrc, sdst,
                                              gcur, gcsr, scur, scsr, en, sen);

  // ---- hs = (x @ W_gcn) * dinv[row]  (fp32, prescaled epilogue) ----
  { dim3 g(rowblk, 1);
    k_gemm64v3<0><<<g, 256, 0, stream>>>(x, Wg, hs, nullptr, dinv,
                                         nullptr, nullptr, nullptr, (int)n, 64); }

  // ---- xpj = bg + dinv[d] * (hs[d] + sum_s hs[s]) via CSR ----
  k_gcn_csr<<<nodeblk, 256, 0, stream>>>(goff, gcsr, hs, dinv, bg, xpj, (int)n);

  // ---- h2 = xpj @ weight (bf16 channel-major packed) + fused sal ----
  k_gemm_h2<<<rowblk, 256, 0, stream>>>(xpj, Wt, h2p, att, sal, (int)n);

  // ---- fused attention -> xm (aliases h; hs dead) ----
  k_mega<<<nodeblk, 256, 0, stream>>>(soff, scsr, h2p, sal, att, xm, (int)n);

  // ---- a = normalize(xm @ W1) (bf16, aliases xpj) + bsc, fused epilogue ----
  { dim3 g(rowblk, 1);
    k_gemm64v3<2><<<g, 256, 0, stream>>>(xm, W1, nullptr, anorm, nullptr,
                                         W2, b2, bsc, (int)n, 64); }

  // ---- cosine + sigmoid -> out ----
  k_cosout<<<nodeblk, 256, 0, stream>>>(soff, scsr, anorm, bsc, out, (int)n);
}

// Round 11
// 369.779 us; speedup vs baseline: 1.1566x; 1.1492x over previous
//
#include <hip/hip_runtime.h>
#include <math.h>

#define TPB 256
#define NEG_SLOPE 0.2f
#define COS_EPS 1e-8f
#define NH 6
#define GSTRIDE 68   // LDS row stride (floats) for GEMM tiles
#define DCACHE 12    // rows cached in registers per node (slot 0 = self)
#define SALS 8       // sal row stride (floats), 32B-aligned

// ---------- helpers ----------
__device__ inline float wave_sum64(float v) {
  #pragma unroll
  for (int off = 32; off > 0; off >>= 1) v += __shfl_down(v, off);
  return __shfl(v, 0);
}
__device__ inline float wave_max64(float v) {
  #pragma unroll
  for (int off = 32; off > 0; off >>= 1) v = fmaxf(v, __shfl_down(v, off));
  return __shfl(v, 0);
}
__device__ inline unsigned short f2bf(float f) {
  unsigned u = __float_as_uint(f);
  unsigned r = (u + 0x7fffu + ((u >> 16) & 1u)) >> 16;   // RNE
  return (unsigned short)r;
}
__device__ inline float bf2f(unsigned short b) {
  return __uint_as_float(((unsigned)b) << 16);
}
__device__ inline unsigned packbf(float lo, float hi) {
  return (unsigned)f2bf(lo) | ((unsigned)f2bf(hi) << 16);
}
__device__ inline float bflo(unsigned u) { return __uint_as_float(u << 16); }
__device__ inline float bfhi(unsigned u) { return __uint_as_float(u & 0xffff0000u); }

#define GS_LOOP(i, total) \
  for (long i = (long)blockIdx.x * blockDim.x + threadIdx.x; i < (total); \
       i += (long)gridDim.x * blockDim.x)

// ---------- CSR build: ONLY the E real edges (self-loops handled analytically)
// g-graph: key dst=ei1, val src=ei0.  s-graph: key src=ei0, val dst=ei1.
__global__ void k_cnt(const int* __restrict__ src, const int* __restrict__ dst,
                      int* __restrict__ gcnt, int* __restrict__ scnt, long E) {
  GS_LOOP(e, E) {
    atomicAdd(&gcnt[dst[e]], 1);
    atomicAdd(&scnt[src[e]], 1);
  }
}

// phase A: per-tile sums + dinv = rsqrt(gcnt + 2)  (2 self-loop contributions)
__global__ __launch_bounds__(1024)
void k_scanA(const int* __restrict__ gcnt, const int* __restrict__ scnt,
             int* __restrict__ bsum, float* __restrict__ dinv, int n, int nb) {
  const int b = blockIdx.x;
  const bool isS = b >= nb;
  const int tb = isS ? b - nb : b;
  const int* cnt = isS ? scnt : gcnt;
  const int t = threadIdx.x;
  const int i0 = tb * 2048 + 2 * t;
  int v0 = (i0 < n) ? cnt[i0] : 0;
  int v1 = (i0 + 1 < n) ? cnt[i0 + 1] : 0;
  if (!isS) {
    if (i0 < n)     dinv[i0]     = rsqrtf((float)v0 + 2.0f);
    if (i0 + 1 < n) dinv[i0 + 1] = rsqrtf((float)v1 + 2.0f);
  }
  __shared__ int red[16];
  int x = v0 + v1;
  #pragma unroll
  for (int o = 32; o > 0; o >>= 1) x += __shfl_down(x, o);
  const int lane = t & 63, wv = t >> 6;
  if (lane == 0) red[wv] = x;
  __syncthreads();
  if (t < 64) {
    int w = (t < 16) ? red[t] : 0;
    #pragma unroll
    for (int o = 32; o > 0; o >>= 1) w += __shfl_down(w, o);
    if (t == 0) bsum[b] = w;
  }
}

// phase B: exclusive-scan the two halves of bsum (nb each)
__global__ void k_scanB(int* __restrict__ bsum, int nb) {
  const int lane = threadIdx.x;   // 64 threads
  if (nb <= 32) {
    int half = lane >> 5, idx = lane & 31;
    int base = half * nb;
    int v = (idx < nb) ? bsum[base + idx] : 0;
    int orig = v;
    #pragma unroll
    for (int d2 = 1; d2 < 32; d2 <<= 1) {
      int y = __shfl_up(v, d2, 32);
      if (idx >= d2) v += y;
    }
    if (idx < nb) bsum[base + idx] = v - orig;
  } else if (lane == 0) {
    int run = 0;
    for (int i = 0; i < nb; ++i) { int v = bsum[i]; bsum[i] = run; run += v; }
    run = 0;
    for (int i = 0; i < nb; ++i) { int v = bsum[nb + i]; bsum[nb + i] = run; run += v; }
  }
}

// phase C: per-tile scan + writeback of off/cur
__global__ __launch_bounds__(1024)
void k_scanC(const int* __restrict__ gcnt, int* __restrict__ goff, int* __restrict__ gcur,
             const int* __restrict__ scnt, int* __restrict__ soff, int* __restrict__ scur,
             const int* __restrict__ bsum, int n, int nb) {
  const int b = blockIdx.x;
  const bool isS = b >= nb;
  const int tb = isS ? b - nb : b;
  const int* cnt = isS ? scnt : gcnt;
  int* off = isS ? soff : goff;
  int* cur = isS ? scur : gcur;
  const int t = threadIdx.x;
  const int i0 = tb * 2048 + 2 * t;
  int v0 = (i0 < n) ? cnt[i0] : 0;
  int v1 = (i0 + 1 < n) ? cnt[i0 + 1] : 0;
  int s2 = v0 + v1;
  const int lane = t & 63, wv = t >> 6;
  int x = s2;
  #pragma unroll
  for (int d2 = 1; d2 < 64; d2 <<= 1) {
    int y = __shfl_up(x, d2);
    if (lane >= d2) x += y;
  }
  __shared__ int wsum[16];
  if (lane == 63) wsum[wv] = x;
  __syncthreads();
  if (t < 64) {
    int w = (t < 16) ? wsum[t] : 0;
    #pragma unroll
    for (int d2 = 1; d2 < 16; d2 <<= 1) {
      int y = __shfl_up(w, d2);
      if ((int)t >= d2) w += y;
    }
    if (t < 16) wsum[t] = w;
  }
  __syncthreads();
  int ex = x - s2 + (wv ? wsum[wv - 1] : 0) + bsum[b];
  if (i0 < n)     { cur[i0] = ex;          off[i0 + 1] = ex + v0; }
  if (i0 + 1 < n) { cur[i0 + 1] = ex + v0; off[i0 + 2] = ex + v0 + v1; }
  if (i0 == 0) off[0] = 0;
}

__global__ void k_scatter(const int* __restrict__ src, const int* __restrict__ dst,
                          int* __restrict__ gcur, int* __restrict__ gcsr,
                          int* __restrict__ scur, int* __restrict__ scsr, long E) {
  GS_LOOP(e, E) {
    int s = src[e], d = dst[e];
    int p1 = atomicAdd(&gcur[d], 1); gcsr[p1] = s;
    int p2 = atomicAdd(&scur[s], 1); scsr[p2] = d;
  }
}

// ---------- GEMM: A[n][64] @ W[64][Mtot], 64x64 tile, 4x4 reg tile ----------
// MODE 0: fp32 out32.
// MODE 1: bf16 out16, scaled by rowscale[row]  (hs = (x@Wg)*dinv).
// MODE 2: normalized bf16 rows (out16) + bsc[r] = A_row·W2 + b2.
template <int MODE>
__global__ __launch_bounds__(256)
void k_gemm64v3(const float* __restrict__ A, const float* __restrict__ W,
                float* __restrict__ out32, unsigned short* __restrict__ out16,
                const float* __restrict__ rowscale,
                const float* __restrict__ W2, const float* __restrict__ b2,
                float* __restrict__ bsc, int n, int Mtot) {
  __shared__ float At[64 * GSTRIDE];
  __shared__ float Wl[64 * GSTRIDE];
  const int t  = threadIdx.x;
  const int tx = t & 15;
  const int ty = t >> 4;
  const int col0 = blockIdx.y * 64;
  const long row0 = (long)blockIdx.x * 64;

  #pragma unroll
  for (int i = 0; i < 4; ++i) {
    int k = ty + 16 * i;
    float4 wv = *(const float4*)&W[(long)k * Mtot + col0 + 4 * tx];
    *(float4*)&Wl[k * GSTRIDE + 4 * tx] = wv;
  }
  #pragma unroll
  for (int i = 0; i < 4; ++i) {
    int r = ty + 16 * i;
    long gr = row0 + r; if (gr >= n) gr = n - 1;
    float4 av = *(const float4*)&A[gr * 64 + 4 * tx];
    At[(4 * tx + 0) * GSTRIDE + r] = av.x;
    At[(4 * tx + 1) * GSTRIDE + r] = av.y;
    At[(4 * tx + 2) * GSTRIDE + r] = av.z;
    At[(4 * tx + 3) * GSTRIDE + r] = av.w;
  }
  __syncthreads();

  const int c0 = 4 * tx;
  const int r0 = 4 * ty;
  float acc[4][4] = {};
  #pragma unroll
  for (int k = 0; k < 64; ++k) {
    float4 av = *(const float4*)&At[k * GSTRIDE + r0];
    float4 wv = *(const float4*)&Wl[k * GSTRIDE + c0];
    acc[0][0] = fmaf(av.x, wv.x, acc[0][0]); acc[0][1] = fmaf(av.x, wv.y, acc[0][1]);
    acc[0][2] = fmaf(av.x, wv.z, acc[0][2]); acc[0][3] = fmaf(av.x, wv.w, acc[0][3]);
    acc[1][0] = fmaf(av.y, wv.x, acc[1][0]); acc[1][1] = fmaf(av.y, wv.y, acc[1][1]);
    acc[1][2] = fmaf(av.y, wv.z, acc[1][2]); acc[1][3] = fmaf(av.y, wv.w, acc[1][3]);
    acc[2][0] = fmaf(av.z, wv.x, acc[2][0]); acc[2][1] = fmaf(av.z, wv.y, acc[2][1]);
    acc[2][2] = fmaf(av.z, wv.z, acc[2][2]); acc[2][3] = fmaf(av.z, wv.w, acc[2][3]);
    acc[3][0] = fmaf(av.w, wv.x, acc[3][0]); acc[3][1] = fmaf(av.w, wv.y, acc[3][1]);
    acc[3][2] = fmaf(av.w, wv.z, acc[3][2]); acc[3][3] = fmaf(av.w, wv.w, acc[3][3]);
  }

  if constexpr (MODE == 0) {
    #pragma unroll
    for (int i = 0; i < 4; ++i) {
      long gr = row0 + r0 + i;
      if (gr < n)
        *(float4*)&out32[gr * Mtot + col0 + c0] =
          make_float4(acc[i][0], acc[i][1], acc[i][2], acc[i][3]);
    }
  }
  if constexpr (MODE == 1) {
    #pragma unroll
    for (int i = 0; i < 4; ++i) {
      long gr = row0 + r0 + i;
      if (gr < n) {
        float sc = rowscale[gr];
        ushort4 v;
        v.x = f2bf(acc[i][0] * sc); v.y = f2bf(acc[i][1] * sc);
        v.z = f2bf(acc[i][2] * sc); v.w = f2bf(acc[i][3] * sc);
        *(ushort4*)&out16[gr * 64 + c0] = v;
      }
    }
  }
  if constexpr (MODE == 2) {
    float p[4], q[4];
    #pragma unroll
    for (int i = 0; i < 4; ++i) {
      q[i] = acc[i][0]*acc[i][0] + acc[i][1]*acc[i][1] +
             acc[i][2]*acc[i][2] + acc[i][3]*acc[i][3];
      p[i] = At[(c0+0) * GSTRIDE + r0 + i] * W2[c0+0] +
             At[(c0+1) * GSTRIDE + r0 + i] * W2[c0+1] +
             At[(c0+2) * GSTRIDE + r0 + i] * W2[c0+2] +
             At[(c0+3) * GSTRIDE + r0 + i] * W2[c0+3];
    }
    #pragma unroll
    for (int m = 1; m < 16; m <<= 1) {
      #pragma unroll
      for (int i = 0; i < 4; ++i) { p[i] += __shfl_xor(p[i], m); q[i] += __shfl_xor(q[i], m); }
    }
    float bb = b2[0];
    #pragma unroll
    for (int i = 0; i < 4; ++i) {
      long gr = row0 + r0 + i;
      if (gr < n) {
        float rn = 1.0f / fmaxf(sqrtf(q[i]), COS_EPS);
        ushort4 v;
        v.x = f2bf(acc[i][0] * rn); v.y = f2bf(acc[i][1] * rn);
        v.z = f2bf(acc[i][2] * rn); v.w = f2bf(acc[i][3] * rn);
        *(ushort4*)&out16[gr * 64 + c0] = v;
        if (tx == 0) bsc[gr] = p[i] + bb;
      }
    }
  }
}

// ---------- h2 GEMM: all 384 cols (6 heads) per block, packed channel-major out.
__global__ __launch_bounds__(256)
void k_gemm_h2(const float* __restrict__ A, const float* __restrict__ W,
               unsigned* __restrict__ h2p, const float* __restrict__ att,
               float* __restrict__ sal, int n) {
  __shared__ float At[64 * GSTRIDE];
  __shared__ float Wl[64 * GSTRIDE];
  const int t  = threadIdx.x;
  const int tx = t & 15;
  const int ty = t >> 4;
  const long row0 = (long)blockIdx.x * 64;
  const int c0 = 4 * tx;
  const int r0 = 4 * ty;

  #pragma unroll
  for (int i = 0; i < 4; ++i) {
    int r = ty + 16 * i;
    long gr = row0 + r; if (gr >= n) gr = n - 1;
    float4 av = *(const float4*)&A[gr * 64 + 4 * tx];
    At[(4 * tx + 0) * GSTRIDE + r] = av.x;
    At[(4 * tx + 1) * GSTRIDE + r] = av.y;
    At[(4 * tx + 2) * GSTRIDE + r] = av.z;
    At[(4 * tx + 3) * GSTRIDE + r] = av.w;
  }
  float4 wr[4];
  #pragma unroll
  for (int i = 0; i < 4; ++i)
    wr[i] = *(const float4*)&W[(long)(ty + 16 * i) * 384 + 4 * tx];

  float4 acc[6][4];
  #pragma unroll
  for (int h = 0; h < 6; ++h)
    #pragma unroll
    for (int i = 0; i < 4; ++i) acc[h][i] = make_float4(0.f, 0.f, 0.f, 0.f);

  #pragma unroll
  for (int head = 0; head < 6; ++head) {
    #pragma unroll
    for (int i = 0; i < 4; ++i)
      *(float4*)&Wl[(ty + 16 * i) * GSTRIDE + 4 * tx] = wr[i];
    __syncthreads();
    if (head < 5) {
      #pragma unroll
      for (int i = 0; i < 4; ++i)
        wr[i] = *(const float4*)&W[(long)(ty + 16 * i) * 384 + (head + 1) * 64 + 4 * tx];
    }
    #pragma unroll 16
    for (int k = 0; k < 64; ++k) {
      float4 av = *(const float4*)&At[k * GSTRIDE + r0];
      float4 wv = *(const float4*)&Wl[k * GSTRIDE + c0];
      acc[head][0].x = fmaf(av.x, wv.x, acc[head][0].x);
      acc[head][0].y = fmaf(av.x, wv.y, acc[head][0].y);
      acc[head][0].z = fmaf(av.x, wv.z, acc[head][0].z);
      acc[head][0].w = fmaf(av.x, wv.w, acc[head][0].w);
      acc[head][1].x = fmaf(av.y, wv.x, acc[head][1].x);
      acc[head][1].y = fmaf(av.y, wv.y, acc[head][1].y);
      acc[head][1].z = fmaf(av.y, wv.z, acc[head][1].z);
      acc[head][1].w = fmaf(av.y, wv.w, acc[head][1].w);
      acc[head][2].x = fmaf(av.z, wv.x, acc[head][2].x);
      acc[head][2].y = fmaf(av.z, wv.y, acc[head][2].y);
      acc[head][2].z = fmaf(av.z, wv.z, acc[head][2].z);
      acc[head][2].w = fmaf(av.z, wv.w, acc[head][2].w);
      acc[head][3].x = fmaf(av.w, wv.x, acc[head][3].x);
      acc[head][3].y = fmaf(av.w, wv.y, acc[head][3].y);
      acc[head][3].z = fmaf(av.w, wv.z, acc[head][3].z);
      acc[head][3].w = fmaf(av.w, wv.w, acc[head][3].w);
    }
    __syncthreads();
  }

  #pragma unroll
  for (int i = 0; i < 4; ++i) {
    long gr = row0 + r0 + i;
    if (gr < n) {
      uint4 u0, u1, u2;
      u0.x = packbf(acc[0][i].x, acc[1][i].x);
      u0.y = packbf(acc[2][i].x, acc[3][i].x);
      u0.z = packbf(acc[4][i].x, acc[5][i].x);
      u0.w = packbf(acc[0][i].y, acc[1][i].y);
      u1.x = packbf(acc[2][i].y, acc[3][i].y);
      u1.y = packbf(acc[4][i].y, acc[5][i].y);
      u1.z = packbf(acc[0][i].z, acc[1][i].z);
      u1.w = packbf(acc[2][i].z, acc[3][i].z);
      u2.x = packbf(acc[4][i].z, acc[5][i].z);
      u2.y = packbf(acc[0][i].w, acc[1][i].w);
      u2.z = packbf(acc[2][i].w, acc[3][i].w);
      u2.w = packbf(acc[4][i].w, acc[5][i].w);
      unsigned* dstp = &h2p[gr * 192 + c0 * 3];
      *(uint4*)(dstp + 0) = u0;
      *(uint4*)(dstp + 4) = u1;
      *(uint4*)(dstp + 8) = u2;
    }
  }
  #pragma unroll
  for (int head = 0; head < 6; ++head) {
    float a0 = att[head * 128 + c0 + 0], a1 = att[head * 128 + c0 + 1];
    float a2 = att[head * 128 + c0 + 2], a3 = att[head * 128 + c0 + 3];
    float p[4];
    #pragma unroll
    for (int i = 0; i < 4; ++i)
      p[i] = acc[head][i].x * a0 + acc[head][i].y * a1 +
             acc[head][i].z * a2 + acc[head][i].w * a3;
    #pragma unroll
    for (int m = 1; m < 16; m <<= 1) {
      #pragma unroll
      for (int i = 0; i < 4; ++i) p[i] += __shfl_xor(p[i], m);
    }
    if (tx == 0) {
      #pragma unroll
      for (int i = 0; i < 4; ++i) {
        long gr = row0 + r0 + i;
        if (gr < n) sal[gr * SALS + head] = p[i];
      }
    }
  }
}

// ---------- GCN aggregate via CSR (wave per node, paired lanes, bf16 rows) ----
// hs32: bf16 pairs of (x@Wg)*dinv[row].  xpj = bg + dinv[d]*(2*hs[d] + sum hs[s])
__global__ __launch_bounds__(256)
void k_gcnb(const int* __restrict__ goff, const int* __restrict__ gcsr,
            const unsigned* __restrict__ hs32, const float* __restrict__ dinv,
            const float* __restrict__ bg, float* __restrict__ xpj, int n) {
  const int lane = threadIdx.x & 63;
  const int p = lane & 31;       // channel pair
  const int hf = lane >> 5;      // which of 2 concurrent edges
  const int d = blockIdx.x * 4 + (threadIdx.x >> 6);
  if (d >= n) return;
  const int o0 = goff[d], o1 = goff[d + 1];
  float ax = 0.f, ay = 0.f;
  for (int j = o0 + hf; j < o1; j += 2) {
    long s = gcsr[j];
    unsigned u = hs32[s * 32 + p];
    ax += bflo(u); ay += bfhi(u);
  }
  ax += __shfl_xor(ax, 32);
  ay += __shfl_xor(ay, 32);
  if (hf == 0) {
    unsigned us = hs32[(long)d * 32 + p];
    float di = dinv[d];
    float2 bv = *(const float2*)&bg[2 * p];
    float2 r;
    r.x = bv.x + di * (ax + 2.0f * bflo(us));
    r.y = bv.y + di * (ay + 2.0f * bfhi(us));
    *(float2*)&xpj[(long)d * 64 + 2 * p] = r;
  }
}

// ---------- fused attention mega-kernel (wave per node; self handled inline) --
__global__ __launch_bounds__(256)
void k_mega(const int* __restrict__ soff, const int* __restrict__ scsr,
            const unsigned* __restrict__ h2p, const float* __restrict__ sal,
            const float* __restrict__ att, float* __restrict__ xm, int n) {
  const int lane = threadIdx.x & 63;
  const int d = blockIdx.x * 4 + (threadIdx.x >> 6);
  if (d >= n) return;
  const int o0 = soff[d], o1 = soff[d + 1];
  const int deg = o1 - o0;       // CSR edges (self excluded)
  const int td  = deg + 1;       // + self

  // ---- pass 1: hmax over self + CSR rows; cache slot 0 = self ----
  unsigned ck0[DCACHE], ck1[DCACHE], ck2[DCACHE];
  float hm[NH];
  {
    const unsigned* rp = &h2p[(long)d * 192 + lane * 3];
    unsigned u0 = rp[0], u1 = rp[1], u2 = rp[2];
    ck0[0] = u0; ck1[0] = u1; ck2[0] = u2;
    hm[0] = bflo(u0); hm[1] = bfhi(u0);
    hm[2] = bflo(u1); hm[3] = bfhi(u1);
    hm[4] = bflo(u2); hm[5] = bfhi(u2);
  }
  #pragma unroll
  for (int idx = 1; idx < DCACHE; ++idx) {
    unsigned u0 = 0, u1 = 0, u2 = 0;
    if (idx < td) {
      long s = scsr[o0 + idx - 1];
      const unsigned* rp = &h2p[s * 192 + lane * 3];
      u0 = rp[0]; u1 = rp[1]; u2 = rp[2];
      hm[0] = fmaxf(hm[0], bflo(u0)); hm[1] = fmaxf(hm[1], bfhi(u0));
      hm[2] = fmaxf(hm[2], bflo(u1)); hm[3] = fmaxf(hm[3], bfhi(u1));
      hm[4] = fmaxf(hm[4], bflo(u2)); hm[5] = fmaxf(hm[5], bfhi(u2));
    }
    ck0[idx] = u0; ck1[idx] = u1; ck2[idx] = u2;
  }
  for (int j = o0 + DCACHE - 1; j < o1; ++j) {
    long s = scsr[j];
    const unsigned* rp = &h2p[s * 192 + lane * 3];
    unsigned u0 = rp[0], u1 = rp[1], u2 = rp[2];
    hm[0] = fmaxf(hm[0], bflo(u0)); hm[1] = fmaxf(hm[1], bfhi(u0));
    hm[2] = fmaxf(hm[2], bflo(u1)); hm[3] = fmaxf(hm[3], bfhi(u1));
    hm[4] = fmaxf(hm[4], bflo(u2)); hm[5] = fmaxf(hm[5], bfhi(u2));
  }

  float dal[NH];
  #pragma unroll
  for (int h = 0; h < NH; ++h)
    dal[h] = wave_sum64(hm[h] * att[h * 128 + 64 + lane]);

  float acc[NH], den[NH];
  #pragma unroll
  for (int h = 0; h < NH; ++h) acc[h] = 0.f;

  if (td <= 64) {
    // ---- fast path: lane = edge (0 = self), one-shot softmax ----
    const bool act = lane < td;
    float4 sA = make_float4(0, 0, 0, 0), sB = sA;
    if (act) {
      int sE = (lane == 0) ? d : scsr[o0 + lane - 1];
      const float4* sp = (const float4*)&sal[(long)sE * SALS];
      sA = sp[0]; sB = sp[1];
    }
    float svv[NH] = {sA.x, sA.y, sA.z, sA.w, sB.x, sB.y};
    float e6[NH];
    #pragma unroll
    for (int h = 0; h < NH; ++h) {
      float al = svv[h] + dal[h];
      al = (al >= 0.f) ? al : NEG_SLOPE * al;
      float a = act ? al : -INFINITY;
      float mx = wave_max64(a);
      e6[h] = act ? expf(a - mx) : 0.f;
      den[h] = wave_sum64(e6[h]);
    }
    #pragma unroll
    for (int idx = 0; idx < DCACHE; ++idx) {
      if (idx < td) {
        float w0 = __shfl(e6[0], idx), w1 = __shfl(e6[1], idx);
        float w2 = __shfl(e6[2], idx), w3 = __shfl(e6[3], idx);
        float w4 = __shfl(e6[4], idx), w5 = __shfl(e6[5], idx);
        acc[0] = fmaf(bflo(ck0[idx]), w0, acc[0]);
        acc[1] = fmaf(bfhi(ck0[idx]), w1, acc[1]);
        acc[2] = fmaf(bflo(ck1[idx]), w2, acc[2]);
        acc[3] = fmaf(bfhi(ck1[idx]), w3, acc[3]);
        acc[4] = fmaf(bflo(ck2[idx]), w4, acc[4]);
        acc[5] = fmaf(bfhi(ck2[idx]), w5, acc[5]);
      }
    }
    for (int j = o0 + DCACHE - 1; j < o1; ++j) {
      int ii = j - o0 + 1;              // edge index (self = 0)
      long s = scsr[j];
      const unsigned* rp = &h2p[s * 192 + lane * 3];
      unsigned u0 = rp[0], u1 = rp[1], u2 = rp[2];
      float w0 = __shfl(e6[0], ii), w1 = __shfl(e6[1], ii);
      float w2 = __shfl(e6[2], ii), w3 = __shfl(e6[3], ii);
      float w4 = __shfl(e6[4], ii), w5 = __shfl(e6[5], ii);
      acc[0] = fmaf(bflo(u0), w0, acc[0]);
      acc[1] = fmaf(bfhi(u0), w1, acc[1]);
      acc[2] = fmaf(bflo(u1), w2, acc[2]);
      acc[3] = fmaf(bfhi(u1), w3, acc[3]);
      acc[4] = fmaf(bflo(u2), w4, acc[4]);
      acc[5] = fmaf(bfhi(u2), w5, acc[5]);
    }
  } else {
    // ---- slow path (td > 64): self handled analytically, then CSR blocks ----
    float asf[NH];
    {
      const float4* sp = (const float4*)&sal[(long)d * SALS];
      float4 sA = sp[0], sB = sp[1];
      float svv[NH] = {sA.x, sA.y, sA.z, sA.w, sB.x, sB.y};
      #pragma unroll
      for (int h = 0; h < NH; ++h) {
        float al = svv[h] + dal[h];
        asf[h] = (al >= 0.f) ? al : NEG_SLOPE * al;
      }
    }
    float mx[NH];
    #pragma unroll
    for (int h = 0; h < NH; ++h) mx[h] = asf[h];
    for (int base = o0; base < o1; base += 64) {
      int j = base + lane;
      float a6[NH];
      if (j < o1) {
        long s = scsr[j];
        const float4* sp = (const float4*)&sal[s * SALS];
        float4 sA = sp[0], sB = sp[1];
        float svv[NH] = {sA.x, sA.y, sA.z, sA.w, sB.x, sB.y};
        #pragma unroll
        for (int h = 0; h < NH; ++h) {
          float al = svv[h] + dal[h];
          a6[h] = (al >= 0.f) ? al : NEG_SLOPE * al;
        }
      } else {
        #pragma unroll
        for (int h = 0; h < NH; ++h) a6[h] = -INFINITY;
      }
      #pragma unroll
      for (int h = 0; h < NH; ++h) mx[h] = fmaxf(mx[h], wave_max64(a6[h]));
    }
    // self contribution
    #pragma unroll
    for (int h = 0; h < NH; ++h) {
      float es = expf(asf[h] - mx[h]);
      den[h] = es;
    }
    acc[0] = bflo(ck0[0]) * den[0]; acc[1] = bfhi(ck0[0]) * den[1];
    acc[2] = bflo(ck1[0]) * den[2]; acc[3] = bfhi(ck1[0]) * den[3];
    acc[4] = bflo(ck2[0]) * den[4]; acc[5] = bfhi(ck2[0]) * den[5];
    for (int base = o0; base < o1; base += 64) {
      int cs = o1 - base; if (cs > 64) cs = 64;
      int j = base + lane;
      float e6[NH]; int s = 0;
      if (j < o1) {
        s = scsr[j];
        const float4* sp = (const float4*)&sal[(long)s * SALS];
        float4 sA = sp[0], sB = sp[1];
        float svv[NH] = {sA.x, sA.y, sA.z, sA.w, sB.x, sB.y};
        #pragma unroll
        for (int h = 0; h < NH; ++h) {
          float al = svv[h] + dal[h];
          al = (al >= 0.f) ? al : NEG_SLOPE * al;
          e6[h] = expf(al - mx[h]);
        }
      } else {
        #pragma unroll
        for (int h = 0; h < NH; ++h) e6[h] = 0.f;
      }
      #pragma unroll
      for (int h = 0; h < NH; ++h) den[h] += wave_sum64(e6[h]);
      for (int jj = 0; jj < cs; ++jj) {
        int sj = __shfl(s, jj);
        const unsigned* rp = &h2p[(long)sj * 192 + lane * 3];
        unsigned u0 = rp[0], u1 = rp[1], u2 = rp[2];
        float w0 = __shfl(e6[0], jj), w1 = __shfl(e6[1], jj);
        float w2 = __shfl(e6[2], jj), w3 = __shfl(e6[3], jj);
        float w4 = __shfl(e6[4], jj), w5 = __shfl(e6[5], jj);
        acc[0] = fmaf(bflo(u0), w0, acc[0]);
        acc[1] = fmaf(bfhi(u0), w1, acc[1]);
        acc[2] = fmaf(bflo(u1), w2, acc[2]);
        acc[3] = fmaf(bfhi(u1), w3, acc[3]);
        acc[4] = fmaf(bflo(u2), w4, acc[4]);
        acc[5] = fmaf(bfhi(u2), w5, acc[5]);
      }
    }
  }

  float o = 0.f;
  #pragma unroll
  for (int h = 0; h < NH; ++h) o += acc[h] / den[h];
  xm[(long)d * 64 + lane] = o * (1.0f / NH);
}

// fitness[d] = sigmoid(bsc[d] * (1 + sum_CSR dot(an[s], an[d])))
// paired lanes: half 0 = even edges, half 1 = odd edges; lane handles ch-pair.
__global__ __launch_bounds__(256)
void k_cosout(const int* __restrict__ soff, const int* __restrict__ scsr,
              const unsigned* __restrict__ an32, const float* __restrict__ bsc,
              float* __restrict__ out, int n) {
  const int lane = threadIdx.x & 63;
  const int p = lane & 31;
  const int hf = lane >> 5;
  const int d = blockIdx.x * 4 + (threadIdx.x >> 6);
  if (d >= n) return;
  const int o0 = soff[d], o1 = soff[d + 1];
  unsigned ud = an32[(long)d * 32 + p];
  float adx = bflo(ud), ady = bfhi(ud);
  float cl = 0.f;
  for (int j = o0 + hf; j < o1; j += 2) {
    long s = scsr[j];
    unsigned u = an32[s * 32 + p];
    cl += adx * bflo(u) + ady * bfhi(u);
  }
  float cs = wave_sum64(cl) + 1.0f;   // self-cosine == 1 exactly
  if (lane == 0) out[d] = 1.0f / (1.0f + expf(-bsc[d] * cs));
}

// ---------- launcher ----------
static inline unsigned gsblocks(long total) {
  long b = (total + TPB - 1) / TPB;
  if (b > 131072) b = 131072;
  return (unsigned)b;
}

extern "C" void kernel_launch(void* const* d_in, const int* in_sizes, int n_in,
                              void* d_out, int out_size, void* d_ws, size_t ws_size,
                              hipStream_t stream) {
  const float* x   = (const float*)d_in[0];
  const float* Wg  = (const float*)d_in[1];
  const float* bg  = (const float*)d_in[2];
  const float* Wt  = (const float*)d_in[3];
  const float* att = (const float*)d_in[4];
  const float* W1  = (const float*)d_in[5];
  const float* W2  = (const float*)d_in[6];
  const float* b2  = (const float*)d_in[7];
  const int* src   = (const int*)d_in[8];
  const int* dst   = (const int*)d_in[9];

  const long n   = in_sizes[0] / 64;   // 50000
  const long en  = in_sizes[8];        // E + N
  const long E   = en - n;             // real edges (ei), loops excluded
  const int  nb  = (int)((n + 2047) / 2048);

  char* base = (char*)d_ws;
  size_t off = 0;
  auto alloc = [&](size_t bytes) -> void* {
    void* p = base + off;
    off += (bytes + 255) & ~(size_t)255;
    return p;
  };
  int*   gcnt = (int*)alloc(n * 4);
  int*   scnt = (int*)alloc(n * 4);   // contiguous with gcnt (one memset)
  int*   goff = (int*)alloc((n + 1) * 4);
  int*   soff = (int*)alloc((n + 1) * 4);
  int*   gcur = (int*)alloc(n * 4);
  int*   scur = (int*)alloc(n * 4);
  int*   gcsr = (int*)alloc(E * 4);
  int*   scsr = (int*)alloc(E * 4);
  int*   bsum = (int*)alloc(2 * (size_t)nb * 4);
  float* dinv = (float*)alloc(n * 4);
  unsigned* hs32 = (unsigned*)alloc(n * 32 * 4);      // bf16 pairs of (x@Wg)*dinv
  float* xpj  = (float*)alloc(n * 64 * 4);            // later anorm (bf16)
  float* xmb  = (float*)alloc(n * 64 * 4);            // xm buffer
  unsigned* h2p = (unsigned*)alloc(n * 192 * 4);      // channel-major bf16 pairs
  float* sal  = (float*)alloc(n * SALS * 4);
  float* bsc  = (float*)alloc(n * 4);
  unsigned short* anorm = (unsigned short*)xpj;       // alias (xpj dead after h2)
  float* out  = (float*)d_out;

  const unsigned rowblk  = (unsigned)((n + 63) / 64);
  const unsigned nodeblk = (unsigned)((n + 3) / 4);

  // ---- CSR build (E edges only; self-loops analytic) + dinv ----
  hipMemsetAsync(gcnt, 0, (size_t)((char*)scnt - (char*)gcnt) + n * 4, stream);
  k_cnt<<<gsblocks(E), TPB, 0, stream>>>(src, dst, gcnt, scnt, E);
  k_scanA<<<2 * nb, 1024, 0, stream>>>(gcnt, scnt, bsum, dinv, (int)n, nb);
  k_scanB<<<1, 64, 0, stream>>>(bsum, nb);
  k_scanC<<<2 * nb, 1024, 0, stream>>>(gcnt, goff, gcur, scnt, soff, scur,
                                       bsum, (int)n, nb);
  k_scatter<<<gsblocks(E), TPB, 0, stream>>>(src, dst, gcur, gcsr, scur, scsr, E);

  // ---- hs = (x @ W_gcn) * dinv[row], bf16 ----
  { dim3 g(rowblk, 1);
    k_gemm64v3<1><<<g, 256, 0, stream>>>(x, Wg, nullptr, (unsigned short*)hs32,
                                         dinv, nullptr, nullptr, nullptr, (int)n, 64); }

  // ---- xpj = bg + dinv[d] * (2*hs[d] + sum_CSR hs[s]) ----
  k_gcnb<<<nodeblk, 256, 0, stream>>>(goff, gcsr, hs32, dinv, bg, xpj, (int)n);

  // ---- h2 = xpj @ weight (bf16 channel-major packed) + fused sal ----
  k_gemm_h2<<<rowblk, 256, 0, stream>>>(xpj, Wt, h2p, att, sal, (int)n);

  // ---- fused attention (self inline) -> xm ----
  k_mega<<<nodeblk, 256, 0, stream>>>(soff, scsr, h2p, sal, att, xmb, (int)n);

  // ---- a = normalize(xm @ W1) (bf16, aliases xpj) + bsc ----
  { dim3 g(rowblk, 1);
    k_gemm64v3<2><<<g, 256, 0, stream>>>(xmb, W1, nullptr, anorm, nullptr,
                                         W2, b2, bsc, (int)n, 64); }

  // ---- cosine + sigmoid -> out (self-cos = 1 analytic) ----
  k_cosout<<<nodeblk, 256, 0, stream>>>(soff, scsr, (const unsigned*)anorm,
                                        bsc, out, (int)n);
}